// Round 4
// baseline (3185.981 us; speedup 1.0000x reference)
//
#include <hip/hip_runtime.h>

// SiameseGNN round 4: two-level dst-bucketing replaces the CSR build.
//
// Round-3 evidence: k_fill_csr 130us x2 with WRITE_SIZE=105MB for a 6.4MB
// array -- random 4B stores over the full array get ~16x write amplification
// (partial-line writebacks from many XCD L2s). k_count_int (1.6M global
// atomics) is the same class. Fix: bucket edges by dst (bucket = dst>>7,
// K=782) with per-block LDS counting + segment reservation, so each output
// line is written by <=2 blocks (L2 merges it); then degrees and the
// aggregation itself consume the bucketed packed edges directly:
//   - per-bucket 128x64 fp32 accumulator in LDS, ds_add_f32 (2-way bank
//     alias = free), Hs[src] gathers bf16 128B/wave (unchanged L3-bound
//     traffic, the true floor)
//   - no csr_src, no row_ptr, no scans, no global atomics on node arrays.
// packed edge = (dstLocal<<17) | src  (7+17 = 24 bits, N=100000 < 2^17).

#define TPB    256
#define CHUNK  128      // nodes per bucket
#define SHIFT  7
#define KMAX   1024     // max buckets supported (N <= 131072)
#define CAP    4096     // temp capacity per bucket (mean 2048, sigma ~45)
#define EPB    8192     // edges per binA block

__device__ __forceinline__ float bf2f(unsigned short u) {
    union { unsigned int i; float f; } c; c.i = ((unsigned int)u) << 16; return c.f;
}
__device__ __forceinline__ unsigned short f2bf(float x) {
    union { float f; unsigned int i; } c; c.f = x;
    unsigned int r = c.i + 0x7FFFu + ((c.i >> 16) & 1u);   // RNE
    return (unsigned short)(r >> 16);
}

__global__ void k_zero_int(int* __restrict__ p, int n) {
    int i = blockIdx.x * blockDim.x + threadIdx.x;
    if (i < n) p[i] = 0;
}

// Bucket edges by dst. Per block: LDS count -> reserve global segment per
// bucket (1 atomic per block-bucket pair) -> write packed edges.
__global__ __launch_bounds__(256) void k_binA(const int* __restrict__ src,
                                              const int* __restrict__ dst,
                                              int* __restrict__ cursorG,
                                              unsigned int* __restrict__ temp,
                                              int E, int K) {
    __shared__ int cnt[KMAX];
    __shared__ int segBase[KMAX];
    int tid = threadIdx.x;
    for (int b = tid; b < K; b += 256) cnt[b] = 0;
    __syncthreads();
    int base = blockIdx.x * EPB;
#pragma unroll
    for (int k = 0; k < EPB / 256; ++k) {
        int e = base + k * 256 + tid;
        if (e < E) atomicAdd(&cnt[dst[e] >> SHIFT], 1);
    }
    __syncthreads();
    for (int b = tid; b < K; b += 256) {
        int c = cnt[b];
        segBase[b] = c ? atomicAdd(&cursorG[b], c) : 0;
        cnt[b] = 0;                       // reuse as local rank cursor
    }
    __syncthreads();
#pragma unroll
    for (int k = 0; k < EPB / 256; ++k) {
        int e = base + k * 256 + tid;
        if (e < E) {
            int d = dst[e];
            int b = d >> SHIFT;
            int pos = segBase[b] + atomicAdd(&cnt[b], 1);
            if (pos < CAP)
                temp[(size_t)b * CAP + pos] =
                    ((unsigned int)(d & (CHUNK - 1)) << 17) | (unsigned int)src[e];
        }
    }
}

// Per bucket: degree count in LDS -> dinv (coalesced). No global atomics.
__global__ __launch_bounds__(256) void k_dinv_bucket(const unsigned int* __restrict__ temp,
                                                     const int* __restrict__ cursorG,
                                                     float* __restrict__ dinv, int N) {
    __shared__ int deg[CHUNK];
    int b = blockIdx.x, tid = threadIdx.x;
    if (tid < CHUNK) deg[tid] = 0;
    __syncthreads();
    int cnt = cursorG[b]; if (cnt > CAP) cnt = CAP;
    const size_t tb = (size_t)b * CAP;
    for (int i = tid; i < cnt; i += 256) {
        unsigned int p = temp[tb + i];
        atomicAdd(&deg[p >> 17], 1);
    }
    __syncthreads();
    int node = b * CHUNK + tid;
    if (tid < CHUNK && node < N) dinv[node] = rsqrtf((float)deg[tid] + 1.0f);
}

// Hs[row, c] = bf16( dinv[row] * sum_k X[row, k] * W[k, c] )
__global__ __launch_bounds__(256) void k_gemm64(const float* __restrict__ X,
                                                const float* __restrict__ W,
                                                const float* __restrict__ dinv,
                                                unsigned short* __restrict__ Hs, int n) {
    __shared__ float Ws[64 * 64];
    __shared__ float Xs[4 * 64];
    int tid = threadIdx.x;
    for (int i = tid; i < 64 * 64; i += 256) Ws[i] = W[i];
    int row0 = blockIdx.x * 4;
    int idx = row0 * 64 + tid;
    Xs[tid] = (idx < n * 64) ? X[idx] : 0.0f;
    __syncthreads();
    int r = tid >> 6, c = tid & 63;
    int row = row0 + r;
    if (row < n) {
        float acc = 0.0f;
#pragma unroll
        for (int k = 0; k < 64; ++k) acc += Xs[r * 64 + k] * Ws[k * 64 + c];
        Hs[(size_t)row * 64 + c] = f2bf(acc * dinv[row]);
    }
}

// Accumulate bucket b's incoming messages into acc[CHUNK*64] (LDS).
// 4 waves share 256-edge staged batches; each wave: broadcast-read packed,
// gather 128B bf16 row of Hs, ds_add_f32 into acc (2-way bank alias, free).
__device__ __forceinline__ void agg_bucket(float* acc, unsigned int* stage,
                                           const unsigned short* __restrict__ Hs,
                                           const unsigned int* __restrict__ temp,
                                           int cnt, int b) {
    int tid = threadIdx.x;
    for (int i = tid; i < CHUNK * 64; i += 256) acc[i] = 0.0f;
    int w = tid >> 6, lane = tid & 63;
    const size_t tb = (size_t)b * CAP;
    for (int base0 = 0; base0 < cnt; base0 += 256) {
        __syncthreads();                       // acc-zero done / prev batch consumed
        if (base0 + tid < cnt) stage[tid] = temp[tb + base0 + tid];
        __syncthreads();
        int m = cnt - base0; if (m > 256) m = 256;
        int j = w;
        for (; j + 28 < m; j += 32) {          // 8 edges/wave-iter for load ILP
            unsigned int p0 = stage[j],      p1 = stage[j + 4],
                         p2 = stage[j + 8],  p3 = stage[j + 12],
                         p4 = stage[j + 16], p5 = stage[j + 20],
                         p6 = stage[j + 24], p7 = stage[j + 28];
            float h0 = bf2f(Hs[(size_t)(p0 & 0x1FFFFu) * 64 + lane]);
            float h1 = bf2f(Hs[(size_t)(p1 & 0x1FFFFu) * 64 + lane]);
            float h2 = bf2f(Hs[(size_t)(p2 & 0x1FFFFu) * 64 + lane]);
            float h3 = bf2f(Hs[(size_t)(p3 & 0x1FFFFu) * 64 + lane]);
            float h4 = bf2f(Hs[(size_t)(p4 & 0x1FFFFu) * 64 + lane]);
            float h5 = bf2f(Hs[(size_t)(p5 & 0x1FFFFu) * 64 + lane]);
            float h6 = bf2f(Hs[(size_t)(p6 & 0x1FFFFu) * 64 + lane]);
            float h7 = bf2f(Hs[(size_t)(p7 & 0x1FFFFu) * 64 + lane]);
            atomicAdd(&acc[(p0 >> 17) * 64 + lane], h0);
            atomicAdd(&acc[(p1 >> 17) * 64 + lane], h1);
            atomicAdd(&acc[(p2 >> 17) * 64 + lane], h2);
            atomicAdd(&acc[(p3 >> 17) * 64 + lane], h3);
            atomicAdd(&acc[(p4 >> 17) * 64 + lane], h4);
            atomicAdd(&acc[(p5 >> 17) * 64 + lane], h5);
            atomicAdd(&acc[(p6 >> 17) * 64 + lane], h6);
            atomicAdd(&acc[(p7 >> 17) * 64 + lane], h7);
        }
        for (; j < m; j += 4) {
            unsigned int p = stage[j];
            float h = bf2f(Hs[(size_t)(p & 0x1FFFFu) * 64 + lane]);
            atomicAdd(&acc[(p >> 17) * 64 + lane], h);
        }
    }
    __syncthreads();
}

// layer 1: A[node, f] = relu(b[f] + dinv[node] * (acc + Hs[node]))
__global__ __launch_bounds__(256) void k_aggL1(const unsigned short* __restrict__ Hs,
                                               const unsigned int* __restrict__ temp,
                                               const int* __restrict__ cursorG,
                                               const float* __restrict__ dinv,
                                               const float* __restrict__ bias,
                                               float* __restrict__ A, int N) {
    __shared__ float acc[CHUNK * 64];
    __shared__ unsigned int stage[256];
    int b = blockIdx.x;
    int cnt = cursorG[b]; if (cnt > CAP) cnt = CAP;
    agg_bucket(acc, stage, Hs, temp, cnt, b);
    int tid = threadIdx.x;
    for (int i = tid; i < CHUNK * 64; i += 256) {
        int node = b * CHUNK + (i >> 6);
        if (node < N) {
            int f = i & 63;
            float v = bias[f] + dinv[node] * (acc[i] + bf2f(Hs[(size_t)node * 64 + f]));
            A[(size_t)node * 64 + f] = fmaxf(v, 0.0f);
        }
    }
}

// layer 2: P[b, f] = sum over bucket nodes of relu(...)  (A never materialized)
__global__ __launch_bounds__(256) void k_aggL2(const unsigned short* __restrict__ Hs,
                                               const unsigned int* __restrict__ temp,
                                               const int* __restrict__ cursorG,
                                               const float* __restrict__ dinv,
                                               const float* __restrict__ bias,
                                               float* __restrict__ P, int N) {
    __shared__ float acc[CHUNK * 64];
    __shared__ unsigned int stage[256];
    __shared__ float red[256];
    int b = blockIdx.x;
    int cnt = cursorG[b]; if (cnt > CAP) cnt = CAP;
    agg_bucket(acc, stage, Hs, temp, cnt, b);
    int tid = threadIdx.x;
    float partial = 0.0f;
    for (int i = tid; i < CHUNK * 64; i += 256) {   // f = tid&63 fixed per thread
        int node = b * CHUNK + (i >> 6);
        if (node < N) {
            int f = i & 63;
            float v = bias[f] + dinv[node] * (acc[i] + bf2f(Hs[(size_t)node * 64 + f]));
            partial += fmaxf(v, 0.0f);
        }
    }
    red[tid] = partial;
    __syncthreads();
    if (tid < 64)
        P[(size_t)b * 64 + tid] = red[tid] + red[tid + 64] + red[tid + 128] + red[tid + 192];
}

__global__ void k_zero64(float* __restrict__ S) {
    if (threadIdx.x < 64) S[threadIdx.x] = 0.0f;
}

__global__ void k_colsum(const float* __restrict__ P, float* __restrict__ S, int rows) {
    int f = threadIdx.x;  // 0..63
    float acc = 0.0f;
    for (int r = blockIdx.x; r < rows; r += gridDim.x) acc += P[r * 64 + f];
    atomicAdd(&S[f], acc);
}

__global__ void k_fc(const float* __restrict__ S, const float* __restrict__ fcw,
                     const float* __restrict__ fcb, float* __restrict__ out, int n) {
    int j = threadIdx.x;  // 0..63
    float inv = 1.0f / (float)n;
    float acc = fcb[j];
#pragma unroll
    for (int k = 0; k < 64; ++k) acc += (S[k] * inv) * fcw[j * 64 + k];
    out[j] = acc;
}

extern "C" void kernel_launch(void* const* d_in, const int* in_sizes, int n_in,
                              void* d_out, int out_size, void* d_ws, size_t ws_size,
                              hipStream_t stream) {
    const float* x[2]  = {(const float*)d_in[0], (const float*)d_in[1]};
    const int*   ei[2] = {(const int*)d_in[2], (const int*)d_in[3]};
    const float* W1  = (const float*)d_in[4];
    const float* b1  = (const float*)d_in[5];
    const float* W2  = (const float*)d_in[6];
    const float* b2  = (const float*)d_in[7];
    const float* fcw = (const float*)d_in[8];
    const float* fcb = (const float*)d_in[9];
    float* out = (float*)d_out;

    const int N  = in_sizes[0] / 64;
    const int E  = in_sizes[2] / 2;
    const int NF = N * 64;
    const int K  = (N + CHUNK - 1) / CHUNK;   // buckets (782 for N=100000)

    // workspace layout (~52 MB)
    float* A             = (float*)d_ws;                        // NF fp32 (25.6 MB)
    unsigned int* temp   = (unsigned int*)(A + (size_t)NF);     // K*CAP   (12.8 MB)
    float* P             = (float*)(temp + (size_t)K * CAP);    // K*64
    float* dinv          = P + (size_t)K * 64;                  // N
    int*   cursorG       = (int*)(dinv + (size_t)N);            // K
    float* S             = (float*)(cursorG + K);               // 64
    unsigned short* Hs   = (unsigned short*)(S + 64);           // NF bf16 (12.8 MB)

    const int gGm  = (N + 3) / 4;
    const int gBin = (E + EPB - 1) / EPB;
    const int gK   = (K + TPB - 1) / TPB;

    for (int g = 0; g < 2; ++g) {
        const int* esrc = ei[g];
        const int* edst = ei[g] + E;

        // bucket build + degrees
        k_zero_int<<<gK, TPB, 0, stream>>>(cursorG, K);
        k_binA<<<gBin, 256, 0, stream>>>(esrc, edst, cursorG, temp, E, K);
        k_dinv_bucket<<<K, 256, 0, stream>>>(temp, cursorG, dinv, N);

        // layer 1
        k_gemm64<<<gGm, TPB, 0, stream>>>(x[g], W1, dinv, Hs, N);
        k_aggL1<<<K, 256, 0, stream>>>(Hs, temp, cursorG, dinv, b1, A, N);

        // layer 2
        k_gemm64<<<gGm, TPB, 0, stream>>>(A, W2, dinv, Hs, N);
        k_aggL2<<<K, 256, 0, stream>>>(Hs, temp, cursorG, dinv, b2, P, N);

        // mean-pool + FC
        k_zero64<<<1, 64, 0, stream>>>(S);
        k_colsum<<<256, 64, 0, stream>>>(P, S, K);
        k_fc<<<1, 64, 0, stream>>>(S, fcw, fcb, out + g * 64, N);
    }
}

// Round 5
// 689.331 us; speedup vs baseline: 4.6218x; 4.6218x over previous
//
#include <hip/hip_runtime.h>

// SiameseGNN round 5: round-3 gather aggregation + bucketed CSR build.
//
// R4 post-mortem: bucket-resident LDS aggregation collapsed parallelism
// (782 blocks, 33KB LDS, serial edge chain -> 704us, VALUBusy 3%). The
// gathers were never the problem; CSR-build write amplification was
// (R3 k_fill_csr: 105MB WRITE for 6.4MB payload). So: keep R3's per-node
// wave aggregate (25K blocks, latency-hidden), rebuild CSR via buckets:
//   binA: edges -> per-bucket packed segments (contiguous writes)
//   scanK: bucket bases (one small scan)
//   csr_bucket: per-bucket LDS counting sort -> contiguous csr_src slice,
//               fused degree count + dinv (kills k_count_int too)
// packed edge = (dstLocal<<17)|src, 7+17=24 bits (N=100000 < 2^17).

#define TPB    256
#define CHUNK  128      // nodes per bucket
#define SHIFT  7
#define KMAX   1024     // max buckets (N <= 131072)
#define CAP    4096     // per-bucket capacity (mean 2046, sigma ~45)
#define EPB    8192     // edges per binA block

__device__ __forceinline__ float bf2f(unsigned short u) {
    union { unsigned int i; float f; } c; c.i = ((unsigned int)u) << 16; return c.f;
}
__device__ __forceinline__ unsigned short f2bf(float x) {
    union { float f; unsigned int i; } c; c.f = x;
    unsigned int r = c.i + 0x7FFFu + ((c.i >> 16) & 1u);   // RNE
    return (unsigned short)(r >> 16);
}

__global__ void k_zero_int(int* __restrict__ p, int n) {
    int i = blockIdx.x * blockDim.x + threadIdx.x;
    if (i < n) p[i] = 0;
}

// Bucket edges by dst. Per block: LDS count -> reserve global segment per
// bucket (1 atomic per block-bucket pair) -> write packed edges.
__global__ __launch_bounds__(256) void k_binA(const int* __restrict__ src,
                                              const int* __restrict__ dst,
                                              int* __restrict__ cursorG,
                                              unsigned int* __restrict__ temp,
                                              int E, int K) {
    __shared__ int cnt[KMAX];
    __shared__ int segBase[KMAX];
    int tid = threadIdx.x;
    for (int b = tid; b < K; b += 256) cnt[b] = 0;
    __syncthreads();
    int base = blockIdx.x * EPB;
#pragma unroll
    for (int k = 0; k < EPB / 256; ++k) {
        int e = base + k * 256 + tid;
        if (e < E) atomicAdd(&cnt[dst[e] >> SHIFT], 1);
    }
    __syncthreads();
    for (int b = tid; b < K; b += 256) {
        int c = cnt[b];
        segBase[b] = c ? atomicAdd(&cursorG[b], c) : 0;
        cnt[b] = 0;                       // reuse as local rank cursor
    }
    __syncthreads();
#pragma unroll
    for (int k = 0; k < EPB / 256; ++k) {
        int e = base + k * 256 + tid;
        if (e < E) {
            int d = dst[e];
            int b = d >> SHIFT;
            int pos = segBase[b] + atomicAdd(&cnt[b], 1);
            if (pos < CAP)
                temp[(size_t)b * CAP + pos] =
                    ((unsigned int)(d & (CHUNK - 1)) << 17) | (unsigned int)src[e];
        }
    }
}

// Exclusive scan of per-bucket counts -> bucketBase; row_ptr[N] = E.
__global__ __launch_bounds__(1024) void k_scanK(const int* __restrict__ cursorG,
                                                int* __restrict__ bucketBase,
                                                int* __restrict__ row_ptr,
                                                int K, int N, int E) {
    __shared__ int s[1024];
    int tid = threadIdx.x;
    int v = (tid < K) ? cursorG[tid] : 0;
    s[tid] = v;
    __syncthreads();
#pragma unroll
    for (int off = 1; off < 1024; off <<= 1) {
        int t = (tid >= off) ? s[tid - off] : 0;
        __syncthreads();
        s[tid] += t;
        __syncthreads();
    }
    if (tid < K) bucketBase[tid] = s[tid] - v;
    if (tid == 0) row_ptr[N] = E;
}

// Per bucket: degree count (LDS) -> dinv + row_ptr; local counting sort ->
// contiguous csr_src slice. All global writes coalesced/contiguous.
__global__ __launch_bounds__(256) void k_csr_bucket(const unsigned int* __restrict__ temp,
                                                    const int* __restrict__ cursorG,
                                                    const int* __restrict__ bucketBase,
                                                    int* __restrict__ csr_src,
                                                    int* __restrict__ row_ptr,
                                                    float* __restrict__ dinv, int N) {
    __shared__ int deg[CHUNK];
    __shared__ int lofs[CHUNK];
    __shared__ int cur[CHUNK];
    int b = blockIdx.x, tid = threadIdx.x;
    if (tid < CHUNK) deg[tid] = 0;
    __syncthreads();
    int cnt = cursorG[b]; if (cnt > CAP) cnt = CAP;
    const size_t tb = (size_t)b * CAP;
    for (int i = tid; i < cnt; i += 256) atomicAdd(&deg[temp[tb + i] >> 17], 1);
    __syncthreads();
    if (tid < CHUNK) lofs[tid] = deg[tid];
    __syncthreads();
#pragma unroll
    for (int off = 1; off < CHUNK; off <<= 1) {      // inclusive scan, 128 lanes
        int t = (tid < CHUNK && tid >= off) ? lofs[tid - off] : 0;
        __syncthreads();
        if (tid < CHUNK) lofs[tid] += t;
        __syncthreads();
    }
    int base = bucketBase[b];
    if (tid < CHUNK) {
        int excl = lofs[tid] - deg[tid];
        lofs[tid] = excl;
        cur[tid] = 0;
        int node = b * CHUNK + tid;
        if (node < N) {
            row_ptr[node] = base + excl;
            dinv[node] = rsqrtf((float)deg[tid] + 1.0f);
        }
    }
    __syncthreads();
    for (int i = tid; i < cnt; i += 256) {
        unsigned int p = temp[tb + i];
        int dl = p >> 17;
        int rank = atomicAdd(&cur[dl], 1);
        csr_src[base + lofs[dl] + rank] = (int)(p & 0x1FFFFu);
    }
}

// Hs[row, c] = bf16( dinv[row] * sum_k X[row, k] * W[k, c] )
__global__ __launch_bounds__(256) void k_gemm64(const float* __restrict__ X,
                                                const float* __restrict__ W,
                                                const float* __restrict__ dinv,
                                                unsigned short* __restrict__ Hs, int n) {
    __shared__ float Ws[64 * 64];
    __shared__ float Xs[4 * 64];
    int tid = threadIdx.x;
    for (int i = tid; i < 64 * 64; i += 256) Ws[i] = W[i];
    int row0 = blockIdx.x * 4;
    int idx = row0 * 64 + tid;
    Xs[tid] = (idx < n * 64) ? X[idx] : 0.0f;
    __syncthreads();
    int r = tid >> 6, c = tid & 63;
    int row = row0 + r;
    if (row < n) {
        float acc = 0.0f;
#pragma unroll
        for (int k = 0; k < 64; ++k) acc += Xs[r * 64 + k] * Ws[k * 64 + c];
        Hs[(size_t)row * 64 + c] = f2bf(acc * dinv[row]);
    }
}

__device__ __forceinline__ float agg_node(const unsigned short* __restrict__ Hs,
                                          const int* __restrict__ csr_src,
                                          const int* __restrict__ row_ptr,
                                          int node, int lane) {
    int beg = __builtin_amdgcn_readfirstlane(row_ptr[node]);
    int end = __builtin_amdgcn_readfirstlane(row_ptr[node + 1]);
    float acc = bf2f(Hs[(size_t)node * 64 + lane]);   // self-loop (dinv-scaled)
    int j = beg;
    for (; j + 3 < end; j += 4) {
        int s0 = __builtin_amdgcn_readfirstlane(csr_src[j]);
        int s1 = __builtin_amdgcn_readfirstlane(csr_src[j + 1]);
        int s2 = __builtin_amdgcn_readfirstlane(csr_src[j + 2]);
        int s3 = __builtin_amdgcn_readfirstlane(csr_src[j + 3]);
        float a0 = bf2f(Hs[(size_t)s0 * 64 + lane]);
        float a1 = bf2f(Hs[(size_t)s1 * 64 + lane]);
        float a2 = bf2f(Hs[(size_t)s2 * 64 + lane]);
        float a3 = bf2f(Hs[(size_t)s3 * 64 + lane]);
        acc += (a0 + a1) + (a2 + a3);
    }
    for (; j < end; ++j) {
        int s0 = __builtin_amdgcn_readfirstlane(csr_src[j]);
        acc += bf2f(Hs[(size_t)s0 * 64 + lane]);
    }
    return acc;
}

// layer-1: A[d, f] = relu(b[f] + dinv[d] * agg)   (fp32, feeds gemm2)
__global__ __launch_bounds__(256) void k_aggregate1(const unsigned short* __restrict__ Hs,
                                                    const int* __restrict__ csr_src,
                                                    const int* __restrict__ row_ptr,
                                                    const float* __restrict__ dinv,
                                                    const float* __restrict__ bias,
                                                    float* __restrict__ A, int n) {
    int node = blockIdx.x * 4 + (threadIdx.x >> 6);
    int lane = threadIdx.x & 63;
    if (node >= n) return;
    float acc = agg_node(Hs, csr_src, row_ptr, node, lane);
    float v = bias[lane] + dinv[node] * acc;
    A[(size_t)node * 64 + lane] = fmaxf(v, 0.0f);
}

// layer-2: block-reduce 4 relu'd rows -> P[block, f]  (A never materialized)
__global__ __launch_bounds__(256) void k_aggregate2(const unsigned short* __restrict__ Hs,
                                                    const int* __restrict__ csr_src,
                                                    const int* __restrict__ row_ptr,
                                                    const float* __restrict__ dinv,
                                                    const float* __restrict__ bias,
                                                    float* __restrict__ P, int n) {
    __shared__ float red[256];
    int node = blockIdx.x * 4 + (threadIdx.x >> 6);
    int lane = threadIdx.x & 63;
    float val = 0.0f;
    if (node < n) {
        float acc = agg_node(Hs, csr_src, row_ptr, node, lane);
        val = fmaxf(bias[lane] + dinv[node] * acc, 0.0f);
    }
    red[threadIdx.x] = val;
    __syncthreads();
    if (threadIdx.x < 64)
        P[(size_t)blockIdx.x * 64 + threadIdx.x] =
            red[threadIdx.x] + red[64 + threadIdx.x] +
            red[128 + threadIdx.x] + red[192 + threadIdx.x];
}

__global__ void k_zero64(float* __restrict__ S) {
    if (threadIdx.x < 64) S[threadIdx.x] = 0.0f;
}

__global__ void k_colsum(const float* __restrict__ P, float* __restrict__ S, int rows) {
    int f = threadIdx.x;  // 0..63
    float acc = 0.0f;
    for (int r = blockIdx.x; r < rows; r += gridDim.x) acc += P[r * 64 + f];
    atomicAdd(&S[f], acc);
}

__global__ void k_fc(const float* __restrict__ S, const float* __restrict__ fcw,
                     const float* __restrict__ fcb, float* __restrict__ out, int n) {
    int j = threadIdx.x;  // 0..63
    float inv = 1.0f / (float)n;
    float acc = fcb[j];
#pragma unroll
    for (int k = 0; k < 64; ++k) acc += (S[k] * inv) * fcw[j * 64 + k];
    out[j] = acc;
}

extern "C" void kernel_launch(void* const* d_in, const int* in_sizes, int n_in,
                              void* d_out, int out_size, void* d_ws, size_t ws_size,
                              hipStream_t stream) {
    const float* x[2]  = {(const float*)d_in[0], (const float*)d_in[1]};
    const int*   ei[2] = {(const int*)d_in[2], (const int*)d_in[3]};
    const float* W1  = (const float*)d_in[4];
    const float* b1  = (const float*)d_in[5];
    const float* W2  = (const float*)d_in[6];
    const float* b2  = (const float*)d_in[7];
    const float* fcw = (const float*)d_in[8];
    const float* fcb = (const float*)d_in[9];
    float* out = (float*)d_out;

    const int N  = in_sizes[0] / 64;
    const int E  = in_sizes[2] / 2;
    const int NF = N * 64;
    const int K  = (N + CHUNK - 1) / CHUNK;   // 782 buckets for N=100000
    const int gGm = (N + 3) / 4;              // gemm/aggregate blocks

    // workspace (~52 MB). temp ALIASES A: temp is dead once csr_src is
    // built, before the first aggregate writes A.
    float* A             = (float*)d_ws;                      // NF fp32 (25.6 MB)
    unsigned int* temp   = (unsigned int*)d_ws;               // K*CAP (12.8 MB) <= A
    unsigned short* Hs   = (unsigned short*)(A + (size_t)NF); // NF bf16 (12.8 MB)
    int*   csr_src       = (int*)(Hs + (size_t)NF);           // E (6.4 MB)
    int*   row_ptr       = csr_src + (size_t)E;               // N+1
    float* dinv          = (float*)(row_ptr + (size_t)(N+1)); // N
    int*   cursorG       = (int*)(dinv + (size_t)N);          // K
    int*   bucketBase    = cursorG + K;                       // K
    float* P             = (float*)(bucketBase + K);          // gGm*64 (6.4 MB)
    float* S             = P + (size_t)gGm * 64;              // 64

    const int gBin = (E + EPB - 1) / EPB;
    const int gK   = (K + TPB - 1) / TPB;

    for (int g = 0; g < 2; ++g) {
        const int* esrc = ei[g];
        const int* edst = ei[g] + E;

        // bucketed CSR build (+ degrees/dinv fused)
        k_zero_int<<<gK, TPB, 0, stream>>>(cursorG, K);
        k_binA<<<gBin, 256, 0, stream>>>(esrc, edst, cursorG, temp, E, K);
        k_scanK<<<1, 1024, 0, stream>>>(cursorG, bucketBase, row_ptr, K, N, E);
        k_csr_bucket<<<K, 256, 0, stream>>>(temp, cursorG, bucketBase,
                                            csr_src, row_ptr, dinv, N);

        // layer 1
        k_gemm64<<<gGm, TPB, 0, stream>>>(x[g], W1, dinv, Hs, N);
        k_aggregate1<<<gGm, TPB, 0, stream>>>(Hs, csr_src, row_ptr, dinv, b1, A, N);

        // layer 2 (A not re-materialized; column partials P instead)
        k_gemm64<<<gGm, TPB, 0, stream>>>(A, W2, dinv, Hs, N);
        k_aggregate2<<<gGm, TPB, 0, stream>>>(Hs, csr_src, row_ptr, dinv, b2, P, N);

        // mean-pool + FC
        k_zero64<<<1, 64, 0, stream>>>(S);
        k_colsum<<<256, 64, 0, stream>>>(P, S, gGm);
        k_fc<<<1, 64, 0, stream>>>(S, fcw, fcb, out + g * 64, N);
    }
}

// Round 6
// 573.092 us; speedup vs baseline: 5.5593x; 1.2028x over previous
//
#include <hip/hip_runtime.h>

// SiameseGNN round 6: MFMA bf16 GEMMs replace the LDS-bound VALU gemm.
//
// R5 evidence: k_gemm64 60us x4, HBM 5.5%, VALUBusy 33% -- one ds_read_b32
// per FMA (Ws stride-256B across k, unvectorizable) = LDS-pipe bound at
// ~13 GF. Fix: 16x16x32 bf16 MFMA, one wave per 16-row tile, no LDS:
//   - Wt[n][k] bf16 pre-transposed once (B-frags = 16B contiguous loads)
//   - dinv folded into the GEMM *input*: Xb = bf16(X*dinv), and aggregate1
//     emits Ab = bf16(dinv*relu(...)) directly (same math as scaling the
//     GEMM output; also halves agg1 write traffic)
//   - verified layouts: A[m=lane&15][k=(lane>>4)*8+j], B mirrored,
//     C/D row=(lane>>4)*4+reg, col=lane&15.
// Everything else (bucketed CSR build, per-node wave gather aggregate,
// pool/FC) unchanged from R5.

#define TPB    256
#define CHUNK  128
#define SHIFT  7
#define KMAX   1024
#define CAP    4096
#define EPB    8192

typedef __attribute__((ext_vector_type(8))) short short8;
typedef __attribute__((ext_vector_type(4))) float f32x4;

__device__ __forceinline__ float bf2f(unsigned short u) {
    union { unsigned int i; float f; } c; c.i = ((unsigned int)u) << 16; return c.f;
}
__device__ __forceinline__ unsigned short f2bf(float x) {
    union { float f; unsigned int i; } c; c.f = x;
    unsigned int r = c.i + 0x7FFFu + ((c.i >> 16) & 1u);   // RNE
    return (unsigned short)(r >> 16);
}

__global__ void k_zero_int(int* __restrict__ p, int n) {
    int i = blockIdx.x * blockDim.x + threadIdx.x;
    if (i < n) p[i] = 0;
}

// Bucket edges by dst (packed (dstLocal<<17)|src) -- contiguous segment writes.
__global__ __launch_bounds__(256) void k_binA(const int* __restrict__ src,
                                              const int* __restrict__ dst,
                                              int* __restrict__ cursorG,
                                              unsigned int* __restrict__ temp,
                                              int E, int K) {
    __shared__ int cnt[KMAX];
    __shared__ int segBase[KMAX];
    int tid = threadIdx.x;
    for (int b = tid; b < K; b += 256) cnt[b] = 0;
    __syncthreads();
    int base = blockIdx.x * EPB;
#pragma unroll
    for (int k = 0; k < EPB / 256; ++k) {
        int e = base + k * 256 + tid;
        if (e < E) atomicAdd(&cnt[dst[e] >> SHIFT], 1);
    }
    __syncthreads();
    for (int b = tid; b < K; b += 256) {
        int c = cnt[b];
        segBase[b] = c ? atomicAdd(&cursorG[b], c) : 0;
        cnt[b] = 0;
    }
    __syncthreads();
#pragma unroll
    for (int k = 0; k < EPB / 256; ++k) {
        int e = base + k * 256 + tid;
        if (e < E) {
            int d = dst[e];
            int b = d >> SHIFT;
            int pos = segBase[b] + atomicAdd(&cnt[b], 1);
            if (pos < CAP)
                temp[(size_t)b * CAP + pos] =
                    ((unsigned int)(d & (CHUNK - 1)) << 17) | (unsigned int)src[e];
        }
    }
}

__global__ __launch_bounds__(1024) void k_scanK(const int* __restrict__ cursorG,
                                                int* __restrict__ bucketBase,
                                                int* __restrict__ row_ptr,
                                                int K, int N, int E) {
    __shared__ int s[1024];
    int tid = threadIdx.x;
    int v = (tid < K) ? cursorG[tid] : 0;
    s[tid] = v;
    __syncthreads();
#pragma unroll
    for (int off = 1; off < 1024; off <<= 1) {
        int t = (tid >= off) ? s[tid - off] : 0;
        __syncthreads();
        s[tid] += t;
        __syncthreads();
    }
    if (tid < K) bucketBase[tid] = s[tid] - v;
    if (tid == 0) row_ptr[N] = E;
}

// Per-bucket LDS counting sort -> contiguous csr_src slice + row_ptr + dinv.
__global__ __launch_bounds__(256) void k_csr_bucket(const unsigned int* __restrict__ temp,
                                                    const int* __restrict__ cursorG,
                                                    const int* __restrict__ bucketBase,
                                                    int* __restrict__ csr_src,
                                                    int* __restrict__ row_ptr,
                                                    float* __restrict__ dinv, int N) {
    __shared__ int deg[CHUNK];
    __shared__ int lofs[CHUNK];
    __shared__ int cur[CHUNK];
    int b = blockIdx.x, tid = threadIdx.x;
    if (tid < CHUNK) deg[tid] = 0;
    __syncthreads();
    int cnt = cursorG[b]; if (cnt > CAP) cnt = CAP;
    const size_t tb = (size_t)b * CAP;
    for (int i = tid; i < cnt; i += 256) atomicAdd(&deg[temp[tb + i] >> 17], 1);
    __syncthreads();
    if (tid < CHUNK) lofs[tid] = deg[tid];
    __syncthreads();
#pragma unroll
    for (int off = 1; off < CHUNK; off <<= 1) {
        int t = (tid < CHUNK && tid >= off) ? lofs[tid - off] : 0;
        __syncthreads();
        if (tid < CHUNK) lofs[tid] += t;
        __syncthreads();
    }
    int base = bucketBase[b];
    if (tid < CHUNK) {
        int excl = lofs[tid] - deg[tid];
        lofs[tid] = excl;
        cur[tid] = 0;
        int node = b * CHUNK + tid;
        if (node < N) {
            row_ptr[node] = base + excl;
            dinv[node] = rsqrtf((float)deg[tid] + 1.0f);
        }
    }
    __syncthreads();
    for (int i = tid; i < cnt; i += 256) {
        unsigned int p = temp[tb + i];
        int dl = p >> 17;
        int rank = atomicAdd(&cur[dl], 1);
        csr_src[base + lofs[dl] + rank] = (int)(p & 0x1FFFFu);
    }
}

// Wt[n][k] = bf16(W[k][n])  (64x64, one block)
__global__ void k_prepW(const float* __restrict__ W, unsigned short* __restrict__ Wt) {
    for (int i = threadIdx.x; i < 64 * 64; i += 256) {
        int n = i >> 6, k = i & 63;
        Wt[i] = f2bf(W[k * 64 + n]);
    }
}

// Xb[i] = bf16(X[i] * dinv[row])   (float4 in, ushort4 out)
__global__ void k_castX(const float4* __restrict__ X4, const float* __restrict__ dinv,
                        ushort4* __restrict__ Xb4, int n4) {
    int i = blockIdx.x * blockDim.x + threadIdx.x;
    if (i < n4) {
        float d = dinv[i >> 4];           // 16 float4 groups per 64-col row
        float4 v = X4[i];
        ushort4 o;
        o.x = f2bf(v.x * d); o.y = f2bf(v.y * d);
        o.z = f2bf(v.z * d); o.w = f2bf(v.w * d);
        Xb4[i] = o;
    }
}

// Hs[m, n] = bf16( sum_k Xb[m, k] * W[k, n] )  -- Xb pre-scaled by dinv.
// One wave per 16-row tile; 8 MFMAs (4 col-tiles x 2 k-halves); no LDS.
__global__ __launch_bounds__(256) void k_gemm_mfma(const unsigned short* __restrict__ Xb,
                                                   const unsigned short* __restrict__ Wt,
                                                   unsigned short* __restrict__ Hs,
                                                   int nTiles, int N) {
    int wave = threadIdx.x >> 6, lane = threadIdx.x & 63;
    int tile = blockIdx.x * 4 + wave;
    if (tile >= nTiles) return;
    int r = lane & 15, q = lane >> 4;
    // B-frags: B[k=q*8+j+32*kb][n=ct*16+r] = Wt[(ct*16+r)*64 + q*8+32*kb + j]
    short8 bfrag[4][2];
#pragma unroll
    for (int ct = 0; ct < 4; ++ct)
#pragma unroll
        for (int kb = 0; kb < 2; ++kb)
            bfrag[ct][kb] = *(const short8*)(Wt + (ct * 16 + r) * 64 + q * 8 + 32 * kb);
    // A-frags: A[m=r][k=q*8+j+32*kb] = Xb[(row0+r)*64 + q*8+32*kb + j]
    int row0 = tile * 16;
    const unsigned short* xrow = Xb + (size_t)(row0 + r) * 64 + q * 8;
    short8 a0 = *(const short8*)(xrow);
    short8 a1 = *(const short8*)(xrow + 32);
    f32x4 acc[4];
#pragma unroll
    for (int ct = 0; ct < 4; ++ct) {
        acc[ct] = (f32x4){0.0f, 0.0f, 0.0f, 0.0f};
        acc[ct] = __builtin_amdgcn_mfma_f32_16x16x32_bf16(a0, bfrag[ct][0], acc[ct], 0, 0, 0);
        acc[ct] = __builtin_amdgcn_mfma_f32_16x16x32_bf16(a1, bfrag[ct][1], acc[ct], 0, 0, 0);
    }
    // D: row = row0 + q*4 + reg, col = ct*16 + r
#pragma unroll
    for (int reg = 0; reg < 4; ++reg) {
        int row = row0 + q * 4 + reg;
        if (row < N) {
            size_t base = (size_t)row * 64 + r;
#pragma unroll
            for (int ct = 0; ct < 4; ++ct)
                Hs[base + ct * 16] = f2bf(acc[ct][reg]);
        }
    }
}

__device__ __forceinline__ float agg_node(const unsigned short* __restrict__ Hs,
                                          const int* __restrict__ csr_src,
                                          const int* __restrict__ row_ptr,
                                          int node, int lane) {
    int beg = __builtin_amdgcn_readfirstlane(row_ptr[node]);
    int end = __builtin_amdgcn_readfirstlane(row_ptr[node + 1]);
    float acc = bf2f(Hs[(size_t)node * 64 + lane]);   // self-loop (dinv-scaled)
    int j = beg;
    for (; j + 3 < end; j += 4) {
        int s0 = __builtin_amdgcn_readfirstlane(csr_src[j]);
        int s1 = __builtin_amdgcn_readfirstlane(csr_src[j + 1]);
        int s2 = __builtin_amdgcn_readfirstlane(csr_src[j + 2]);
        int s3 = __builtin_amdgcn_readfirstlane(csr_src[j + 3]);
        float a0 = bf2f(Hs[(size_t)s0 * 64 + lane]);
        float a1 = bf2f(Hs[(size_t)s1 * 64 + lane]);
        float a2 = bf2f(Hs[(size_t)s2 * 64 + lane]);
        float a3 = bf2f(Hs[(size_t)s3 * 64 + lane]);
        acc += (a0 + a1) + (a2 + a3);
    }
    for (; j < end; ++j) {
        int s0 = __builtin_amdgcn_readfirstlane(csr_src[j]);
        acc += bf2f(Hs[(size_t)s0 * 64 + lane]);
    }
    return acc;
}

// layer-1: Ab[d, f] = bf16( dinv[d] * relu(b[f] + dinv[d] * agg) )
// (pre-scaled by dinv so gemm2 needs no epilogue scale)
__global__ __launch_bounds__(256) void k_aggregate1(const unsigned short* __restrict__ Hs,
                                                    const int* __restrict__ csr_src,
                                                    const int* __restrict__ row_ptr,
                                                    const float* __restrict__ dinv,
                                                    const float* __restrict__ bias,
                                                    unsigned short* __restrict__ Ab, int n) {
    int node = blockIdx.x * 4 + (threadIdx.x >> 6);
    int lane = threadIdx.x & 63;
    if (node >= n) return;
    float acc = agg_node(Hs, csr_src, row_ptr, node, lane);
    float d = dinv[node];
    float v = fmaxf(bias[lane] + d * acc, 0.0f);
    Ab[(size_t)node * 64 + lane] = f2bf(v * d);
}

// layer-2: block-reduce 4 relu'd rows -> P[block, f]
__global__ __launch_bounds__(256) void k_aggregate2(const unsigned short* __restrict__ Hs,
                                                    const int* __restrict__ csr_src,
                                                    const int* __restrict__ row_ptr,
                                                    const float* __restrict__ dinv,
                                                    const float* __restrict__ bias,
                                                    float* __restrict__ P, int n) {
    __shared__ float red[256];
    int node = blockIdx.x * 4 + (threadIdx.x >> 6);
    int lane = threadIdx.x & 63;
    float val = 0.0f;
    if (node < n) {
        float acc = agg_node(Hs, csr_src, row_ptr, node, lane);
        val = fmaxf(bias[lane] + dinv[node] * acc, 0.0f);
    }
    red[threadIdx.x] = val;
    __syncthreads();
    if (threadIdx.x < 64)
        P[(size_t)blockIdx.x * 64 + threadIdx.x] =
            red[threadIdx.x] + red[64 + threadIdx.x] +
            red[128 + threadIdx.x] + red[192 + threadIdx.x];
}

__global__ void k_zero64(float* __restrict__ S) {
    if (threadIdx.x < 64) S[threadIdx.x] = 0.0f;
}

__global__ void k_colsum(const float* __restrict__ P, float* __restrict__ S, int rows) {
    int f = threadIdx.x;
    float acc = 0.0f;
    for (int r = blockIdx.x; r < rows; r += gridDim.x) acc += P[r * 64 + f];
    atomicAdd(&S[f], acc);
}

__global__ void k_fc(const float* __restrict__ S, const float* __restrict__ fcw,
                     const float* __restrict__ fcb, float* __restrict__ out, int n) {
    int j = threadIdx.x;
    float inv = 1.0f / (float)n;
    float acc = fcb[j];
#pragma unroll
    for (int k = 0; k < 64; ++k) acc += (S[k] * inv) * fcw[j * 64 + k];
    out[j] = acc;
}

extern "C" void kernel_launch(void* const* d_in, const int* in_sizes, int n_in,
                              void* d_out, int out_size, void* d_ws, size_t ws_size,
                              hipStream_t stream) {
    const float* x[2]  = {(const float*)d_in[0], (const float*)d_in[1]};
    const int*   ei[2] = {(const int*)d_in[2], (const int*)d_in[3]};
    const float* W1  = (const float*)d_in[4];
    const float* b1  = (const float*)d_in[5];
    const float* W2  = (const float*)d_in[6];
    const float* b2  = (const float*)d_in[7];
    const float* fcw = (const float*)d_in[8];
    const float* fcb = (const float*)d_in[9];
    float* out = (float*)d_out;

    const int N  = in_sizes[0] / 64;
    const int E  = in_sizes[2] / 2;
    const int NF = N * 64;
    const int K  = (N + CHUNK - 1) / CHUNK;     // 782 buckets
    const int gGm = (N + 3) / 4;                // aggregate blocks (4 nodes each)
    const int nTiles = (N + 15) / 16;           // gemm row-tiles

    // workspace layout (byte offsets, 16B-aligned). temp aliases Xb (temp
    // dead after k_csr_bucket, before k_castX writes Xb).
    char* w = (char*)d_ws;
    size_t off = 0;
    auto alloc = [&](size_t bytes) { void* p = w + off; off += (bytes + 15) & ~15ull; return p; };
    size_t tempB = (size_t)K * CAP * 4;                      // 12.81 MB
    size_t xbB   = ((size_t)NF + 1024) * 2;                  // 12.80 MB (+pad rows)
    void* region0        = alloc(tempB > xbB ? tempB : xbB);
    unsigned int* temp   = (unsigned int*)region0;
    unsigned short* Xb   = (unsigned short*)region0;
    unsigned short* Ab   = (unsigned short*)alloc(((size_t)NF + 1024) * 2);
    unsigned short* Hs   = (unsigned short*)alloc((size_t)NF * 2);
    int*   csr_src       = (int*)alloc((size_t)E * 4);
    int*   row_ptr       = (int*)alloc((size_t)(N + 1) * 4);
    float* dinv          = (float*)alloc((size_t)N * 4);
    int*   cursorG       = (int*)alloc((size_t)K * 4);
    int*   bucketBase    = (int*)alloc((size_t)K * 4);
    float* P             = (float*)alloc((size_t)gGm * 64 * 4);
    float* S             = (float*)alloc(64 * 4);
    unsigned short* Wt1  = (unsigned short*)alloc(64 * 64 * 2);
    unsigned short* Wt2  = (unsigned short*)alloc(64 * 64 * 2);

    const int gBin = (E + EPB - 1) / EPB;
    const int gK   = (K + TPB - 1) / TPB;
    const int gC   = (NF / 4 + TPB - 1) / TPB;
    const int gMf  = (nTiles + 3) / 4;

    // weights shared across both graphs -- prep once
    k_prepW<<<1, 256, 0, stream>>>(W1, Wt1);
    k_prepW<<<1, 256, 0, stream>>>(W2, Wt2);

    for (int g = 0; g < 2; ++g) {
        const int* esrc = ei[g];
        const int* edst = ei[g] + E;

        // bucketed CSR build (+ dinv fused)
        k_zero_int<<<gK, TPB, 0, stream>>>(cursorG, K);
        k_binA<<<gBin, 256, 0, stream>>>(esrc, edst, cursorG, temp, E, K);
        k_scanK<<<1, 1024, 0, stream>>>(cursorG, bucketBase, row_ptr, K, N, E);
        k_csr_bucket<<<K, 256, 0, stream>>>(temp, cursorG, bucketBase,
                                            csr_src, row_ptr, dinv, N);

        // layer 1
        k_castX<<<gC, TPB, 0, stream>>>((const float4*)x[g], dinv, (ushort4*)Xb, NF / 4);
        k_gemm_mfma<<<gMf, 256, 0, stream>>>(Xb, Wt1, Hs, nTiles, N);
        k_aggregate1<<<gGm, TPB, 0, stream>>>(Hs, csr_src, row_ptr, dinv, b1, Ab, N);

        // layer 2
        k_gemm_mfma<<<gMf, 256, 0, stream>>>(Ab, Wt2, Hs, nTiles, N);
        k_aggregate2<<<gGm, TPB, 0, stream>>>(Hs, csr_src, row_ptr, dinv, b2, P, N);

        // mean-pool + FC
        k_zero64<<<1, 64, 0, stream>>>(S);
        k_colsum<<<256, 64, 0, stream>>>(P, S, gGm);
        k_fc<<<1, 64, 0, stream>>>(S, fcw, fcb, out + g * 64, N);
    }
}

// Round 7
// 559.312 us; speedup vs baseline: 5.6962x; 1.0246x over previous
//
#include <hip/hip_runtime.h>

// SiameseGNN round 7: latency-tolerant gather aggregate + castX fused into gemm1.
//
// R6 evidence: 4x aggregate ~52us each, FETCH 89MB, VALUBusy 19%, occupancy
// 73% -- logical gather rate only 3.9 TB/s, under every BW ceiling. The
// unroll-4 loop serializes two memory rounds per 4 edges (wave-uniform
// csr_src loads, then dependent gathers). Fix:
//   - one coalesced csr_src load per <=64 edges (lane i holds index beg+i),
//     __shfl broadcast (VALU) replaces the index-load round entirely
//   - gather unroll x8 -> 8 independent 128B loads in flight per wave
//   - gemm1 loads fp32 X directly (32B/lane), scales by dinv, converts to
//     bf16 in-register: kills k_castX (25.6MB rd + 12.8MB wr + dispatch)
// Everything else unchanged from R6.

#define TPB    256
#define CHUNK  128
#define SHIFT  7
#define KMAX   1024
#define CAP    4096
#define EPB    8192

typedef __attribute__((ext_vector_type(8))) short short8;
typedef __attribute__((ext_vector_type(4))) float f32x4;

__device__ __forceinline__ float bf2f(unsigned short u) {
    union { unsigned int i; float f; } c; c.i = ((unsigned int)u) << 16; return c.f;
}
__device__ __forceinline__ unsigned short f2bf(float x) {
    union { float f; unsigned int i; } c; c.f = x;
    unsigned int r = c.i + 0x7FFFu + ((c.i >> 16) & 1u);   // RNE
    return (unsigned short)(r >> 16);
}

__global__ void k_zero_int(int* __restrict__ p, int n) {
    int i = blockIdx.x * blockDim.x + threadIdx.x;
    if (i < n) p[i] = 0;
}

// Bucket edges by dst (packed (dstLocal<<17)|src) -- contiguous segment writes.
__global__ __launch_bounds__(256) void k_binA(const int* __restrict__ src,
                                              const int* __restrict__ dst,
                                              int* __restrict__ cursorG,
                                              unsigned int* __restrict__ temp,
                                              int E, int K) {
    __shared__ int cnt[KMAX];
    __shared__ int segBase[KMAX];
    int tid = threadIdx.x;
    for (int b = tid; b < K; b += 256) cnt[b] = 0;
    __syncthreads();
    int base = blockIdx.x * EPB;
#pragma unroll
    for (int k = 0; k < EPB / 256; ++k) {
        int e = base + k * 256 + tid;
        if (e < E) atomicAdd(&cnt[dst[e] >> SHIFT], 1);
    }
    __syncthreads();
    for (int b = tid; b < K; b += 256) {
        int c = cnt[b];
        segBase[b] = c ? atomicAdd(&cursorG[b], c) : 0;
        cnt[b] = 0;
    }
    __syncthreads();
#pragma unroll
    for (int k = 0; k < EPB / 256; ++k) {
        int e = base + k * 256 + tid;
        if (e < E) {
            int d = dst[e];
            int b = d >> SHIFT;
            int pos = segBase[b] + atomicAdd(&cnt[b], 1);
            if (pos < CAP)
                temp[(size_t)b * CAP + pos] =
                    ((unsigned int)(d & (CHUNK - 1)) << 17) | (unsigned int)src[e];
        }
    }
}

__global__ __launch_bounds__(1024) void k_scanK(const int* __restrict__ cursorG,
                                                int* __restrict__ bucketBase,
                                                int* __restrict__ row_ptr,
                                                int K, int N, int E) {
    __shared__ int s[1024];
    int tid = threadIdx.x;
    int v = (tid < K) ? cursorG[tid] : 0;
    s[tid] = v;
    __syncthreads();
#pragma unroll
    for (int off = 1; off < 1024; off <<= 1) {
        int t = (tid >= off) ? s[tid - off] : 0;
        __syncthreads();
        s[tid] += t;
        __syncthreads();
    }
    if (tid < K) bucketBase[tid] = s[tid] - v;
    if (tid == 0) row_ptr[N] = E;
}

// Per-bucket LDS counting sort -> contiguous csr_src slice + row_ptr + dinv.
__global__ __launch_bounds__(256) void k_csr_bucket(const unsigned int* __restrict__ temp,
                                                    const int* __restrict__ cursorG,
                                                    const int* __restrict__ bucketBase,
                                                    int* __restrict__ csr_src,
                                                    int* __restrict__ row_ptr,
                                                    float* __restrict__ dinv, int N) {
    __shared__ int deg[CHUNK];
    __shared__ int lofs[CHUNK];
    __shared__ int cur[CHUNK];
    int b = blockIdx.x, tid = threadIdx.x;
    if (tid < CHUNK) deg[tid] = 0;
    __syncthreads();
    int cnt = cursorG[b]; if (cnt > CAP) cnt = CAP;
    const size_t tb = (size_t)b * CAP;
    for (int i = tid; i < cnt; i += 256) atomicAdd(&deg[temp[tb + i] >> 17], 1);
    __syncthreads();
    if (tid < CHUNK) lofs[tid] = deg[tid];
    __syncthreads();
#pragma unroll
    for (int off = 1; off < CHUNK; off <<= 1) {
        int t = (tid < CHUNK && tid >= off) ? lofs[tid - off] : 0;
        __syncthreads();
        if (tid < CHUNK) lofs[tid] += t;
        __syncthreads();
    }
    int base = bucketBase[b];
    if (tid < CHUNK) {
        int excl = lofs[tid] - deg[tid];
        lofs[tid] = excl;
        cur[tid] = 0;
        int node = b * CHUNK + tid;
        if (node < N) {
            row_ptr[node] = base + excl;
            dinv[node] = rsqrtf((float)deg[tid] + 1.0f);
        }
    }
    __syncthreads();
    for (int i = tid; i < cnt; i += 256) {
        unsigned int p = temp[tb + i];
        int dl = p >> 17;
        int rank = atomicAdd(&cur[dl], 1);
        csr_src[base + lofs[dl] + rank] = (int)(p & 0x1FFFFu);
    }
}

// Wt[n][k] = bf16(W[k][n])  (64x64, one block)
__global__ void k_prepW(const float* __restrict__ W, unsigned short* __restrict__ Wt) {
    for (int i = threadIdx.x; i < 64 * 64; i += 256) {
        int n = i >> 6, k = i & 63;
        Wt[i] = f2bf(W[k * 64 + n]);
    }
}

// Shared MFMA body: A-fragments provided by caller; B from Wt; store bf16 Hs.
__device__ __forceinline__ void mfma_tail(short8 a0, short8 a1,
                                          const unsigned short* __restrict__ Wt,
                                          unsigned short* __restrict__ Hs,
                                          int row0, int r, int q, int N) {
    short8 bfrag[4][2];
#pragma unroll
    for (int ct = 0; ct < 4; ++ct)
#pragma unroll
        for (int kb = 0; kb < 2; ++kb)
            bfrag[ct][kb] = *(const short8*)(Wt + (ct * 16 + r) * 64 + q * 8 + 32 * kb);
    f32x4 acc[4];
#pragma unroll
    for (int ct = 0; ct < 4; ++ct) {
        acc[ct] = (f32x4){0.0f, 0.0f, 0.0f, 0.0f};
        acc[ct] = __builtin_amdgcn_mfma_f32_16x16x32_bf16(a0, bfrag[ct][0], acc[ct], 0, 0, 0);
        acc[ct] = __builtin_amdgcn_mfma_f32_16x16x32_bf16(a1, bfrag[ct][1], acc[ct], 0, 0, 0);
    }
#pragma unroll
    for (int reg = 0; reg < 4; ++reg) {
        int row = row0 + q * 4 + reg;
        if (row < N) {
            size_t base = (size_t)row * 64 + r;
#pragma unroll
            for (int ct = 0; ct < 4; ++ct)
                Hs[base + ct * 16] = f2bf(acc[ct][reg]);
        }
    }
}

// GEMM1: fp32 X in, dinv folded into A-fragment conversion (castX fused).
__global__ __launch_bounds__(256) void k_gemm_mfma_x(const float* __restrict__ X,
                                                     const float* __restrict__ dinv,
                                                     const unsigned short* __restrict__ Wt,
                                                     unsigned short* __restrict__ Hs,
                                                     int nTiles, int N) {
    int wave = threadIdx.x >> 6, lane = threadIdx.x & 63;
    int tile = blockIdx.x * 4 + wave;
    if (tile >= nTiles) return;
    int r = lane & 15, q = lane >> 4;
    int row0 = tile * 16;
    int row = row0 + r;
    int rr = row < N ? row : N - 1;            // clamp: OOB-safe, masked at store
    float d = dinv[rr];
    const float* xrow = X + (size_t)rr * 64 + q * 8;
    short8 a0, a1;
#pragma unroll
    for (int j = 0; j < 8; ++j) a0[j] = (short)f2bf(xrow[j] * d);
#pragma unroll
    for (int j = 0; j < 8; ++j) a1[j] = (short)f2bf(xrow[32 + j] * d);
    mfma_tail(a0, a1, Wt, Hs, row0, r, q, N);
}

// GEMM2: bf16 Ab in (already dinv-scaled by aggregate1).
__global__ __launch_bounds__(256) void k_gemm_mfma(const unsigned short* __restrict__ Xb,
                                                   const unsigned short* __restrict__ Wt,
                                                   unsigned short* __restrict__ Hs,
                                                   int nTiles, int N) {
    int wave = threadIdx.x >> 6, lane = threadIdx.x & 63;
    int tile = blockIdx.x * 4 + wave;
    if (tile >= nTiles) return;
    int r = lane & 15, q = lane >> 4;
    int row0 = tile * 16;
    const unsigned short* xrow = Xb + (size_t)(row0 + r) * 64 + q * 8;
    short8 a0 = *(const short8*)(xrow);
    short8 a1 = *(const short8*)(xrow + 32);
    mfma_tail(a0, a1, Wt, Hs, row0, r, q, N);
}

// Gather-aggregate for one node: one coalesced index load per <=64 edges,
// __shfl broadcast, gathers unrolled x8 (8 independent 128B loads in flight).
__device__ __forceinline__ float agg_node(const unsigned short* __restrict__ Hs,
                                          const int* __restrict__ csr_src,
                                          const int* __restrict__ row_ptr,
                                          int node, int lane) {
    int beg = __builtin_amdgcn_readfirstlane(row_ptr[node]);
    int end = __builtin_amdgcn_readfirstlane(row_ptr[node + 1]);
    float acc = bf2f(Hs[(size_t)node * 64 + lane]);   // self-loop (dinv-scaled)
    for (int base = beg; base < end; base += 64) {
        int m = end - base; if (m > 64) m = 64;
        int idx = (base + lane < end) ? csr_src[base + lane] : 0;   // coalesced
        int j = 0;
        for (; j + 7 < m; j += 8) {
            int s0 = __shfl(idx, j + 0, 64);
            int s1 = __shfl(idx, j + 1, 64);
            int s2 = __shfl(idx, j + 2, 64);
            int s3 = __shfl(idx, j + 3, 64);
            int s4 = __shfl(idx, j + 4, 64);
            int s5 = __shfl(idx, j + 5, 64);
            int s6 = __shfl(idx, j + 6, 64);
            int s7 = __shfl(idx, j + 7, 64);
            float h0 = bf2f(Hs[(size_t)s0 * 64 + lane]);
            float h1 = bf2f(Hs[(size_t)s1 * 64 + lane]);
            float h2 = bf2f(Hs[(size_t)s2 * 64 + lane]);
            float h3 = bf2f(Hs[(size_t)s3 * 64 + lane]);
            float h4 = bf2f(Hs[(size_t)s4 * 64 + lane]);
            float h5 = bf2f(Hs[(size_t)s5 * 64 + lane]);
            float h6 = bf2f(Hs[(size_t)s6 * 64 + lane]);
            float h7 = bf2f(Hs[(size_t)s7 * 64 + lane]);
            acc += ((h0 + h1) + (h2 + h3)) + ((h4 + h5) + (h6 + h7));
        }
        for (; j < m; ++j) {
            int s = __shfl(idx, j, 64);
            acc += bf2f(Hs[(size_t)s * 64 + lane]);
        }
    }
    return acc;
}

// layer-1: Ab[d, f] = bf16( dinv[d] * relu(b[f] + dinv[d] * agg) )
__global__ __launch_bounds__(256) void k_aggregate1(const unsigned short* __restrict__ Hs,
                                                    const int* __restrict__ csr_src,
                                                    const int* __restrict__ row_ptr,
                                                    const float* __restrict__ dinv,
                                                    const float* __restrict__ bias,
                                                    unsigned short* __restrict__ Ab, int n) {
    int node = blockIdx.x * 4 + (threadIdx.x >> 6);
    int lane = threadIdx.x & 63;
    if (node >= n) return;
    float acc = agg_node(Hs, csr_src, row_ptr, node, lane);
    float d = dinv[node];
    float v = fmaxf(bias[lane] + d * acc, 0.0f);
    Ab[(size_t)node * 64 + lane] = f2bf(v * d);
}

// layer-2: block-reduce 4 relu'd rows -> P[block, f]
__global__ __launch_bounds__(256) void k_aggregate2(const unsigned short* __restrict__ Hs,
                                                    const int* __restrict__ csr_src,
                                                    const int* __restrict__ row_ptr,
                                                    const float* __restrict__ dinv,
                                                    const float* __restrict__ bias,
                                                    float* __restrict__ P, int n) {
    __shared__ float red[256];
    int node = blockIdx.x * 4 + (threadIdx.x >> 6);
    int lane = threadIdx.x & 63;
    float val = 0.0f;
    if (node < n) {
        float acc = agg_node(Hs, csr_src, row_ptr, node, lane);
        val = fmaxf(bias[lane] + dinv[node] * acc, 0.0f);
    }
    red[threadIdx.x] = val;
    __syncthreads();
    if (threadIdx.x < 64)
        P[(size_t)blockIdx.x * 64 + threadIdx.x] =
            red[threadIdx.x] + red[64 + threadIdx.x] +
            red[128 + threadIdx.x] + red[192 + threadIdx.x];
}

__global__ void k_zero64(float* __restrict__ S) {
    if (threadIdx.x < 64) S[threadIdx.x] = 0.0f;
}

__global__ void k_colsum(const float* __restrict__ P, float* __restrict__ S, int rows) {
    int f = threadIdx.x;
    float acc = 0.0f;
    for (int r = blockIdx.x; r < rows; r += gridDim.x) acc += P[r * 64 + f];
    atomicAdd(&S[f], acc);
}

__global__ void k_fc(const float* __restrict__ S, const float* __restrict__ fcw,
                     const float* __restrict__ fcb, float* __restrict__ out, int n) {
    int j = threadIdx.x;
    float inv = 1.0f / (float)n;
    float acc = fcb[j];
#pragma unroll
    for (int k = 0; k < 64; ++k) acc += (S[k] * inv) * fcw[j * 64 + k];
    out[j] = acc;
}

extern "C" void kernel_launch(void* const* d_in, const int* in_sizes, int n_in,
                              void* d_out, int out_size, void* d_ws, size_t ws_size,
                              hipStream_t stream) {
    const float* x[2]  = {(const float*)d_in[0], (const float*)d_in[1]};
    const int*   ei[2] = {(const int*)d_in[2], (const int*)d_in[3]};
    const float* W1  = (const float*)d_in[4];
    const float* b1  = (const float*)d_in[5];
    const float* W2  = (const float*)d_in[6];
    const float* b2  = (const float*)d_in[7];
    const float* fcw = (const float*)d_in[8];
    const float* fcb = (const float*)d_in[9];
    float* out = (float*)d_out;

    const int N  = in_sizes[0] / 64;
    const int E  = in_sizes[2] / 2;
    const int NF = N * 64;
    const int K  = (N + CHUNK - 1) / CHUNK;     // 782 buckets
    const int gGm = (N + 3) / 4;                // aggregate blocks (4 nodes each)
    const int nTiles = (N + 15) / 16;           // gemm row-tiles

    char* w = (char*)d_ws;
    size_t off = 0;
    auto alloc = [&](size_t bytes) { void* p = w + off; off += (bytes + 15) & ~15ull; return p; };
    unsigned int* temp   = (unsigned int*)alloc((size_t)K * CAP * 4);      // 12.8 MB
    unsigned short* Ab   = (unsigned short*)alloc(((size_t)NF + 1024) * 2);
    unsigned short* Hs   = (unsigned short*)alloc((size_t)NF * 2);
    int*   csr_src       = (int*)alloc((size_t)E * 4);
    int*   row_ptr       = (int*)alloc((size_t)(N + 1) * 4);
    float* dinv          = (float*)alloc((size_t)N * 4);
    int*   cursorG       = (int*)alloc((size_t)K * 4);
    int*   bucketBase    = (int*)alloc((size_t)K * 4);
    float* P             = (float*)alloc((size_t)gGm * 64 * 4);
    float* S             = (float*)alloc(64 * 4);
    unsigned short* Wt1  = (unsigned short*)alloc(64 * 64 * 2);
    unsigned short* Wt2  = (unsigned short*)alloc(64 * 64 * 2);

    const int gBin = (E + EPB - 1) / EPB;
    const int gK   = (K + TPB - 1) / TPB;
    const int gMf  = (nTiles + 3) / 4;

    // weights shared across both graphs -- prep once
    k_prepW<<<1, 256, 0, stream>>>(W1, Wt1);
    k_prepW<<<1, 256, 0, stream>>>(W2, Wt2);

    for (int g = 0; g < 2; ++g) {
        const int* esrc = ei[g];
        const int* edst = ei[g] + E;

        // bucketed CSR build (+ dinv fused)
        k_zero_int<<<gK, TPB, 0, stream>>>(cursorG, K);
        k_binA<<<gBin, 256, 0, stream>>>(esrc, edst, cursorG, temp, E, K);
        k_scanK<<<1, 1024, 0, stream>>>(cursorG, bucketBase, row_ptr, K, N, E);
        k_csr_bucket<<<K, 256, 0, stream>>>(temp, cursorG, bucketBase,
                                            csr_src, row_ptr, dinv, N);

        // layer 1 (castX fused into gemm)
        k_gemm_mfma_x<<<gMf, 256, 0, stream>>>(x[g], dinv, Wt1, Hs, nTiles, N);
        k_aggregate1<<<gGm, TPB, 0, stream>>>(Hs, csr_src, row_ptr, dinv, b1, Ab, N);

        // layer 2
        k_gemm_mfma<<<gMf, 256, 0, stream>>>(Ab, Wt2, Hs, nTiles, N);
        k_aggregate2<<<gGm, TPB, 0, stream>>>(Hs, csr_src, row_ptr, dinv, b2, P, N);

        // mean-pool + FC
        k_zero64<<<1, 64, 0, stream>>>(S);
        k_colsum<<<256, 64, 0, stream>>>(P, S, gGm);
        k_fc<<<1, 64, 0, stream>>>(S, fcw, fcb, out + g * 64, N);
    }
}

// Round 9
// 523.572 us; speedup vs baseline: 6.0851x; 1.0683x over previous
//
#include <hip/hip_runtime.h>

// SiameseGNN round 9: R8 multi-row gather aggregate with the divergent-shfl
// bug fixed.
//
// R8 post-mortem: tail path did `if (g < rem) { __shfl(idx, t+g) ... }` --
// ds_bpermute with an exec-INACTIVE source lane (lane t+g is in a masked-off
// group) returns undefined data -> garbage row index for ~1.5 edges on ~3/4
// of nodes -> absmax 9.3e-3 (7% systematic). Fix: hoist the shfl out of the
// divergent branch (all 64 lanes execute it; only g<rem lanes consume).
//
// Aggregate structure (R8 theory, now testable): wave = 4 groups x 16 lanes,
// each group gathers a different src row at 8B/lane (ushort4) -> one VMEM
// instruction covers 4 edges (4x fewer gather insts than R7). Indices via
// one coalesced 64-index load + one shfl per 4 edges; cross-group butterfly
// reduce; epilogue on lanes 0-15.

#define TPB    256
#define CHUNK  128
#define SHIFT  7
#define KMAX   1024
#define CAP    4096
#define EPB    8192

typedef __attribute__((ext_vector_type(8))) short short8;
typedef __attribute__((ext_vector_type(4))) float f32x4;

__device__ __forceinline__ float bf2f(unsigned short u) {
    union { unsigned int i; float f; } c; c.i = ((unsigned int)u) << 16; return c.f;
}
__device__ __forceinline__ unsigned short f2bf(float x) {
    union { float f; unsigned int i; } c; c.f = x;
    unsigned int r = c.i + 0x7FFFu + ((c.i >> 16) & 1u);   // RNE
    return (unsigned short)(r >> 16);
}

__global__ void k_zero_int(int* __restrict__ p, int n) {
    int i = blockIdx.x * blockDim.x + threadIdx.x;
    if (i < n) p[i] = 0;
}

// Bucket edges by dst (packed (dstLocal<<17)|src) -- contiguous segment writes.
__global__ __launch_bounds__(256) void k_binA(const int* __restrict__ src,
                                              const int* __restrict__ dst,
                                              int* __restrict__ cursorG,
                                              unsigned int* __restrict__ temp,
                                              int E, int K) {
    __shared__ int cnt[KMAX];
    __shared__ int segBase[KMAX];
    int tid = threadIdx.x;
    for (int b = tid; b < K; b += 256) cnt[b] = 0;
    __syncthreads();
    int base = blockIdx.x * EPB;
#pragma unroll
    for (int k = 0; k < EPB / 256; ++k) {
        int e = base + k * 256 + tid;
        if (e < E) atomicAdd(&cnt[dst[e] >> SHIFT], 1);
    }
    __syncthreads();
    for (int b = tid; b < K; b += 256) {
        int c = cnt[b];
        segBase[b] = c ? atomicAdd(&cursorG[b], c) : 0;
        cnt[b] = 0;
    }
    __syncthreads();
#pragma unroll
    for (int k = 0; k < EPB / 256; ++k) {
        int e = base + k * 256 + tid;
        if (e < E) {
            int d = dst[e];
            int b = d >> SHIFT;
            int pos = segBase[b] + atomicAdd(&cnt[b], 1);
            if (pos < CAP)
                temp[(size_t)b * CAP + pos] =
                    ((unsigned int)(d & (CHUNK - 1)) << 17) | (unsigned int)src[e];
        }
    }
}

__global__ __launch_bounds__(1024) void k_scanK(const int* __restrict__ cursorG,
                                                int* __restrict__ bucketBase,
                                                int* __restrict__ row_ptr,
                                                int K, int N, int E) {
    __shared__ int s[1024];
    int tid = threadIdx.x;
    int v = (tid < K) ? cursorG[tid] : 0;
    s[tid] = v;
    __syncthreads();
#pragma unroll
    for (int off = 1; off < 1024; off <<= 1) {
        int t = (tid >= off) ? s[tid - off] : 0;
        __syncthreads();
        s[tid] += t;
        __syncthreads();
    }
    if (tid < K) bucketBase[tid] = s[tid] - v;
    if (tid == 0) row_ptr[N] = E;
}

// Per-bucket LDS counting sort -> contiguous csr_src slice + row_ptr + dinv.
__global__ __launch_bounds__(256) void k_csr_bucket(const unsigned int* __restrict__ temp,
                                                    const int* __restrict__ cursorG,
                                                    const int* __restrict__ bucketBase,
                                                    int* __restrict__ csr_src,
                                                    int* __restrict__ row_ptr,
                                                    float* __restrict__ dinv, int N) {
    __shared__ int deg[CHUNK];
    __shared__ int lofs[CHUNK];
    __shared__ int cur[CHUNK];
    int b = blockIdx.x, tid = threadIdx.x;
    if (tid < CHUNK) deg[tid] = 0;
    __syncthreads();
    int cnt = cursorG[b]; if (cnt > CAP) cnt = CAP;
    const size_t tb = (size_t)b * CAP;
    for (int i = tid; i < cnt; i += 256) atomicAdd(&deg[temp[tb + i] >> 17], 1);
    __syncthreads();
    if (tid < CHUNK) lofs[tid] = deg[tid];
    __syncthreads();
#pragma unroll
    for (int off = 1; off < CHUNK; off <<= 1) {
        int t = (tid < CHUNK && tid >= off) ? lofs[tid - off] : 0;
        __syncthreads();
        if (tid < CHUNK) lofs[tid] += t;
        __syncthreads();
    }
    int base = bucketBase[b];
    if (tid < CHUNK) {
        int excl = lofs[tid] - deg[tid];
        lofs[tid] = excl;
        cur[tid] = 0;
        int node = b * CHUNK + tid;
        if (node < N) {
            row_ptr[node] = base + excl;
            dinv[node] = rsqrtf((float)deg[tid] + 1.0f);
        }
    }
    __syncthreads();
    for (int i = tid; i < cnt; i += 256) {
        unsigned int p = temp[tb + i];
        int dl = p >> 17;
        int rank = atomicAdd(&cur[dl], 1);
        csr_src[base + lofs[dl] + rank] = (int)(p & 0x1FFFFu);
    }
}

// Wt[n][k] = bf16(W[k][n])  (64x64, one block)
__global__ void k_prepW(const float* __restrict__ W, unsigned short* __restrict__ Wt) {
    for (int i = threadIdx.x; i < 64 * 64; i += 256) {
        int n = i >> 6, k = i & 63;
        Wt[i] = f2bf(W[k * 64 + n]);
    }
}

// Shared MFMA body: A-fragments provided by caller; B from Wt; store bf16 Hs.
__device__ __forceinline__ void mfma_tail(short8 a0, short8 a1,
                                          const unsigned short* __restrict__ Wt,
                                          unsigned short* __restrict__ Hs,
                                          int row0, int r, int q, int N) {
    short8 bfrag[4][2];
#pragma unroll
    for (int ct = 0; ct < 4; ++ct)
#pragma unroll
        for (int kb = 0; kb < 2; ++kb)
            bfrag[ct][kb] = *(const short8*)(Wt + (ct * 16 + r) * 64 + q * 8 + 32 * kb);
    f32x4 acc[4];
#pragma unroll
    for (int ct = 0; ct < 4; ++ct) {
        acc[ct] = (f32x4){0.0f, 0.0f, 0.0f, 0.0f};
        acc[ct] = __builtin_amdgcn_mfma_f32_16x16x32_bf16(a0, bfrag[ct][0], acc[ct], 0, 0, 0);
        acc[ct] = __builtin_amdgcn_mfma_f32_16x16x32_bf16(a1, bfrag[ct][1], acc[ct], 0, 0, 0);
    }
#pragma unroll
    for (int reg = 0; reg < 4; ++reg) {
        int row = row0 + q * 4 + reg;
        if (row < N) {
            size_t base = (size_t)row * 64 + r;
#pragma unroll
            for (int ct = 0; ct < 4; ++ct)
                Hs[base + ct * 16] = f2bf(acc[ct][reg]);
        }
    }
}

// GEMM1: fp32 X in, dinv folded into A-fragment conversion.
__global__ __launch_bounds__(256) void k_gemm_mfma_x(const float* __restrict__ X,
                                                     const float* __restrict__ dinv,
                                                     const unsigned short* __restrict__ Wt,
                                                     unsigned short* __restrict__ Hs,
                                                     int nTiles, int N) {
    int wave = threadIdx.x >> 6, lane = threadIdx.x & 63;
    int tile = blockIdx.x * 4 + wave;
    if (tile >= nTiles) return;
    int r = lane & 15, q = lane >> 4;
    int row0 = tile * 16;
    int row = row0 + r;
    int rr = row < N ? row : N - 1;
    float d = dinv[rr];
    const float* xrow = X + (size_t)rr * 64 + q * 8;
    short8 a0, a1;
#pragma unroll
    for (int j = 0; j < 8; ++j) a0[j] = (short)f2bf(xrow[j] * d);
#pragma unroll
    for (int j = 0; j < 8; ++j) a1[j] = (short)f2bf(xrow[32 + j] * d);
    mfma_tail(a0, a1, Wt, Hs, row0, r, q, N);
}

// GEMM2: bf16 Ab in (already dinv-scaled by aggregate1).
__global__ __launch_bounds__(256) void k_gemm_mfma(const unsigned short* __restrict__ Xb,
                                                   const unsigned short* __restrict__ Wt,
                                                   unsigned short* __restrict__ Hs,
                                                   int nTiles, int N) {
    int wave = threadIdx.x >> 6, lane = threadIdx.x & 63;
    int tile = blockIdx.x * 4 + wave;
    if (tile >= nTiles) return;
    int r = lane & 15, q = lane >> 4;
    int row0 = tile * 16;
    const unsigned short* xrow = Xb + (size_t)(row0 + r) * 64 + q * 8;
    short8 a0 = *(const short8*)(xrow);
    short8 a1 = *(const short8*)(xrow + 32);
    mfma_tail(a0, a1, Wt, Hs, row0, r, q, N);
}

// Multi-row gather: wave = 4 groups x 16 lanes; group g gathers edge t+g's
// src row at 8B/lane (ushort4). All __shfl ops are executed by ALL 64 lanes
// (exec-uniform); only the consuming gather/add is predicated.
__device__ __forceinline__ void agg_node4(const unsigned short* __restrict__ Hs,
                                          const int* __restrict__ csr_src,
                                          int beg, int end, int lane,
                                          float& a0, float& a1, float& a2, float& a3) {
    int g = lane >> 4, s = lane & 15;
    for (int base = beg; base < end; base += 64) {
        int m = end - base; if (m > 64) m = 64;
        int idx = (lane < m) ? csr_src[base + lane] : 0;   // coalesced
        int t = 0;
        for (; t + 8 <= m; t += 8) {                       // 2 gathers in flight
            int s0 = __shfl(idx, t + g, 64);
            int s1 = __shfl(idx, t + 4 + g, 64);
            ushort4 h0 = *(const ushort4*)(Hs + (size_t)s0 * 64 + s * 4);
            ushort4 h1 = *(const ushort4*)(Hs + (size_t)s1 * 64 + s * 4);
            a0 += bf2f(h0.x) + bf2f(h1.x);
            a1 += bf2f(h0.y) + bf2f(h1.y);
            a2 += bf2f(h0.z) + bf2f(h1.z);
            a3 += bf2f(h0.w) + bf2f(h1.w);
        }
        for (; t + 4 <= m; t += 4) {
            int s0 = __shfl(idx, t + g, 64);
            ushort4 h0 = *(const ushort4*)(Hs + (size_t)s0 * 64 + s * 4);
            a0 += bf2f(h0.x); a1 += bf2f(h0.y); a2 += bf2f(h0.z); a3 += bf2f(h0.w);
        }
        int rem = m - t;
        if (rem > 0) {                    // wave-uniform guard
            // shfl executed by ALL lanes; source lane clamped into [t, m)
            int sl = t + ((g < rem) ? g : 0);
            int s0 = __shfl(idx, sl, 64);
            if (g < rem) {                // divergent CONSUMER only
                ushort4 h0 = *(const ushort4*)(Hs + (size_t)s0 * 64 + s * 4);
                a0 += bf2f(h0.x); a1 += bf2f(h0.y); a2 += bf2f(h0.z); a3 += bf2f(h0.w);
            }
        }
    }
    // cross-group butterfly (bits 4,5): exec-uniform, all lanes end with totals
    a0 += __shfl_xor(a0, 16, 64); a0 += __shfl_xor(a0, 32, 64);
    a1 += __shfl_xor(a1, 16, 64); a1 += __shfl_xor(a1, 32, 64);
    a2 += __shfl_xor(a2, 16, 64); a2 += __shfl_xor(a2, 32, 64);
    a3 += __shfl_xor(a3, 16, 64); a3 += __shfl_xor(a3, 32, 64);
}

// layer-1: Ab[d, f] = bf16( dinv[d] * relu(b[f] + dinv[d] * agg) )
__global__ __launch_bounds__(256) void k_aggregate1(const unsigned short* __restrict__ Hs,
                                                    const int* __restrict__ csr_src,
                                                    const int* __restrict__ row_ptr,
                                                    const float* __restrict__ dinv,
                                                    const float* __restrict__ bias,
                                                    unsigned short* __restrict__ Ab, int n) {
    int wave = threadIdx.x >> 6, lane = threadIdx.x & 63;
    int node = blockIdx.x * 4 + wave;
    if (node >= n) return;
    int beg = __builtin_amdgcn_readfirstlane(row_ptr[node]);
    int end = __builtin_amdgcn_readfirstlane(row_ptr[node + 1]);
    float a0 = 0.f, a1 = 0.f, a2 = 0.f, a3 = 0.f;
    agg_node4(Hs, csr_src, beg, end, lane, a0, a1, a2, a3);
    if ((lane >> 4) == 0) {          // lanes 0..15 hold the result
        int s = lane;
        ushort4 hs = *(const ushort4*)(Hs + (size_t)node * 64 + s * 4);
        float4 bb = *(const float4*)(bias + s * 4);
        float d = dinv[node];
        float v0 = fmaxf(bb.x + d * (a0 + bf2f(hs.x)), 0.0f);
        float v1 = fmaxf(bb.y + d * (a1 + bf2f(hs.y)), 0.0f);
        float v2 = fmaxf(bb.z + d * (a2 + bf2f(hs.z)), 0.0f);
        float v3 = fmaxf(bb.w + d * (a3 + bf2f(hs.w)), 0.0f);
        ushort4 o;
        o.x = f2bf(v0 * d); o.y = f2bf(v1 * d);
        o.z = f2bf(v2 * d); o.w = f2bf(v3 * d);
        *(ushort4*)(Ab + (size_t)node * 64 + s * 4) = o;
    }
}

// layer-2: block-reduce 4 relu'd rows -> P[block, f]  (A never materialized)
__global__ __launch_bounds__(256) void k_aggregate2(const unsigned short* __restrict__ Hs,
                                                    const int* __restrict__ csr_src,
                                                    const int* __restrict__ row_ptr,
                                                    const float* __restrict__ dinv,
                                                    const float* __restrict__ bias,
                                                    float* __restrict__ P, int n) {
    __shared__ float red[256];
    int wave = threadIdx.x >> 6, lane = threadIdx.x & 63;
    int node = blockIdx.x * 4 + wave;
    bool active = node < n;
    int nn = active ? node : (n - 1);
    int beg = __builtin_amdgcn_readfirstlane(row_ptr[nn]);
    int end = __builtin_amdgcn_readfirstlane(row_ptr[nn + 1]);
    if (!active) { beg = 0; end = 0; }
    float a0 = 0.f, a1 = 0.f, a2 = 0.f, a3 = 0.f;
    agg_node4(Hs, csr_src, beg, end, lane, a0, a1, a2, a3);
    if ((lane >> 4) == 0) {
        int s = lane;
        float4 v = {0.f, 0.f, 0.f, 0.f};
        if (active) {
            ushort4 hs = *(const ushort4*)(Hs + (size_t)node * 64 + s * 4);
            float4 bb = *(const float4*)(bias + s * 4);
            float d = dinv[node];
            v.x = fmaxf(bb.x + d * (a0 + bf2f(hs.x)), 0.0f);
            v.y = fmaxf(bb.y + d * (a1 + bf2f(hs.y)), 0.0f);
            v.z = fmaxf(bb.z + d * (a2 + bf2f(hs.z)), 0.0f);
            v.w = fmaxf(bb.w + d * (a3 + bf2f(hs.w)), 0.0f);
        }
        *(float4*)(&red[wave * 64 + s * 4]) = v;
    }
    __syncthreads();
    if (threadIdx.x < 64)
        P[(size_t)blockIdx.x * 64 + threadIdx.x] =
            red[threadIdx.x] + red[64 + threadIdx.x] +
            red[128 + threadIdx.x] + red[192 + threadIdx.x];
}

__global__ void k_zero64(float* __restrict__ S) {
    if (threadIdx.x < 64) S[threadIdx.x] = 0.0f;
}

__global__ void k_colsum(const float* __restrict__ P, float* __restrict__ S, int rows) {
    int f = threadIdx.x;
    float acc = 0.0f;
    for (int r = blockIdx.x; r < rows; r += gridDim.x) acc += P[r * 64 + f];
    atomicAdd(&S[f], acc);
}

__global__ void k_fc(const float* __restrict__ S, const float* __restrict__ fcw,
                     const float* __restrict__ fcb, float* __restrict__ out, int n) {
    int j = threadIdx.x;
    float inv = 1.0f / (float)n;
    float acc = fcb[j];
#pragma unroll
    for (int k = 0; k < 64; ++k) acc += (S[k] * inv) * fcw[j * 64 + k];
    out[j] = acc;
}

extern "C" void kernel_launch(void* const* d_in, const int* in_sizes, int n_in,
                              void* d_out, int out_size, void* d_ws, size_t ws_size,
                              hipStream_t stream) {
    const float* x[2]  = {(const float*)d_in[0], (const float*)d_in[1]};
    const int*   ei[2] = {(const int*)d_in[2], (const int*)d_in[3]};
    const float* W1  = (const float*)d_in[4];
    const float* b1  = (const float*)d_in[5];
    const float* W2  = (const float*)d_in[6];
    const float* b2  = (const float*)d_in[7];
    const float* fcw = (const float*)d_in[8];
    const float* fcb = (const float*)d_in[9];
    float* out = (float*)d_out;

    const int N  = in_sizes[0] / 64;
    const int E  = in_sizes[2] / 2;
    const int NF = N * 64;
    const int K  = (N + CHUNK - 1) / CHUNK;     // 782 buckets
    const int gGm = (N + 3) / 4;                // aggregate blocks (4 nodes each)
    const int nTiles = (N + 15) / 16;           // gemm row-tiles

    char* w = (char*)d_ws;
    size_t off = 0;
    auto alloc = [&](size_t bytes) { void* p = w + off; off += (bytes + 127) & ~127ull; return p; };
    unsigned int* temp   = (unsigned int*)alloc((size_t)K * CAP * 4);      // 12.8 MB
    unsigned short* Ab   = (unsigned short*)alloc(((size_t)NF + 1024) * 2);
    unsigned short* Hs   = (unsigned short*)alloc((size_t)NF * 2);
    int*   csr_src       = (int*)alloc((size_t)E * 4);
    int*   row_ptr       = (int*)alloc((size_t)(N + 1) * 4);
    float* dinv          = (float*)alloc((size_t)N * 4);
    int*   cursorG       = (int*)alloc((size_t)K * 4);
    int*   bucketBase    = (int*)alloc((size_t)K * 4);
    float* P             = (float*)alloc((size_t)gGm * 64 * 4);
    float* S             = (float*)alloc(64 * 4);
    unsigned short* Wt1  = (unsigned short*)alloc(64 * 64 * 2);
    unsigned short* Wt2  = (unsigned short*)alloc(64 * 64 * 2);

    const int gBin = (E + EPB - 1) / EPB;
    const int gK   = (K + TPB - 1) / TPB;
    const int gMf  = (nTiles + 3) / 4;

    // weights shared across both graphs -- prep once
    k_prepW<<<1, 256, 0, stream>>>(W1, Wt1);
    k_prepW<<<1, 256, 0, stream>>>(W2, Wt2);

    for (int g = 0; g < 2; ++g) {
        const int* esrc = ei[g];
        const int* edst = ei[g] + E;

        // bucketed CSR build (+ dinv fused)
        k_zero_int<<<gK, TPB, 0, stream>>>(cursorG, K);
        k_binA<<<gBin, 256, 0, stream>>>(esrc, edst, cursorG, temp, E, K);
        k_scanK<<<1, 1024, 0, stream>>>(cursorG, bucketBase, row_ptr, K, N, E);
        k_csr_bucket<<<K, 256, 0, stream>>>(temp, cursorG, bucketBase,
                                            csr_src, row_ptr, dinv, N);

        // layer 1 (castX fused into gemm)
        k_gemm_mfma_x<<<gMf, 256, 0, stream>>>(x[g], dinv, Wt1, Hs, nTiles, N);
        k_aggregate1<<<gGm, TPB, 0, stream>>>(Hs, csr_src, row_ptr, dinv, b1, Ab, N);

        // layer 2
        k_gemm_mfma<<<gMf, 256, 0, stream>>>(Ab, Wt2, Hs, nTiles, N);
        k_aggregate2<<<gGm, TPB, 0, stream>>>(Hs, csr_src, row_ptr, dinv, b2, P, N);

        // mean-pool + FC
        k_zero64<<<1, 64, 0, stream>>>(S);
        k_colsum<<<256, 64, 0, stream>>>(P, S, gGm);
        k_fc<<<1, 64, 0, stream>>>(S, fcw, fcb, out + g * 64, N);
    }
}

// Round 10
// 499.485 us; speedup vs baseline: 6.3785x; 1.0482x over previous
//
#include <hip/hip_runtime.h>

// SiameseGNN round 10: binA occupancy fix + 8-edges-per-VMEM aggregate.
//
// R9 evidence: k_binA 48us x2 at OccupancyPercent=7% (196 blocks for 256
// CUs), VALUBusy 1.5%, HBM 7% -- pure latency/parallelism starvation.
//   fix 1: EPB 8192->4096 (391 blocks, full CU coverage; segment 21B keeps
//          write-amp ~3x, same as measured).
// R8/R9 validated: fewer gather instructions = faster aggregate (4-edge
// ushort4 scheme pushed aggregates below binA).
//   fix 2: wave = 8 groups x 8 lanes x ushort8 (16B/lane) -> one VMEM
//          instruction covers 8 edges; butterfly xor 8/16/32.
// Everything else unchanged from R9.

#define TPB    256
#define CHUNK  128
#define SHIFT  7
#define KMAX   1024
#define CAP    4096
#define EPB    4096     // edges per binA block (R10: was 8192)

typedef __attribute__((ext_vector_type(8))) short short8;
typedef __attribute__((ext_vector_type(8))) unsigned short ushort8;
typedef __attribute__((ext_vector_type(4))) float f32x4;

__device__ __forceinline__ float bf2f(unsigned short u) {
    union { unsigned int i; float f; } c; c.i = ((unsigned int)u) << 16; return c.f;
}
__device__ __forceinline__ unsigned short f2bf(float x) {
    union { float f; unsigned int i; } c; c.f = x;
    unsigned int r = c.i + 0x7FFFu + ((c.i >> 16) & 1u);   // RNE
    return (unsigned short)(r >> 16);
}

__global__ void k_zero_int(int* __restrict__ p, int n) {
    int i = blockIdx.x * blockDim.x + threadIdx.x;
    if (i < n) p[i] = 0;
}

// Bucket edges by dst (packed (dstLocal<<17)|src) -- contiguous segment writes.
__global__ __launch_bounds__(256) void k_binA(const int* __restrict__ src,
                                              const int* __restrict__ dst,
                                              int* __restrict__ cursorG,
                                              unsigned int* __restrict__ temp,
                                              int E, int K) {
    __shared__ int cnt[KMAX];
    __shared__ int segBase[KMAX];
    int tid = threadIdx.x;
    for (int b = tid; b < K; b += 256) cnt[b] = 0;
    __syncthreads();
    int base = blockIdx.x * EPB;
#pragma unroll
    for (int k = 0; k < EPB / 256; ++k) {
        int e = base + k * 256 + tid;
        if (e < E) atomicAdd(&cnt[dst[e] >> SHIFT], 1);
    }
    __syncthreads();
    for (int b = tid; b < K; b += 256) {
        int c = cnt[b];
        segBase[b] = c ? atomicAdd(&cursorG[b], c) : 0;
        cnt[b] = 0;
    }
    __syncthreads();
#pragma unroll
    for (int k = 0; k < EPB / 256; ++k) {
        int e = base + k * 256 + tid;
        if (e < E) {
            int d = dst[e];
            int b = d >> SHIFT;
            int pos = segBase[b] + atomicAdd(&cnt[b], 1);
            if (pos < CAP)
                temp[(size_t)b * CAP + pos] =
                    ((unsigned int)(d & (CHUNK - 1)) << 17) | (unsigned int)src[e];
        }
    }
}

__global__ __launch_bounds__(1024) void k_scanK(const int* __restrict__ cursorG,
                                                int* __restrict__ bucketBase,
                                                int* __restrict__ row_ptr,
                                                int K, int N, int E) {
    __shared__ int s[1024];
    int tid = threadIdx.x;
    int v = (tid < K) ? cursorG[tid] : 0;
    s[tid] = v;
    __syncthreads();
#pragma unroll
    for (int off = 1; off < 1024; off <<= 1) {
        int t = (tid >= off) ? s[tid - off] : 0;
        __syncthreads();
        s[tid] += t;
        __syncthreads();
    }
    if (tid < K) bucketBase[tid] = s[tid] - v;
    if (tid == 0) row_ptr[N] = E;
}

// Per-bucket LDS counting sort -> contiguous csr_src slice + row_ptr + dinv.
__global__ __launch_bounds__(256) void k_csr_bucket(const unsigned int* __restrict__ temp,
                                                    const int* __restrict__ cursorG,
                                                    const int* __restrict__ bucketBase,
                                                    int* __restrict__ csr_src,
                                                    int* __restrict__ row_ptr,
                                                    float* __restrict__ dinv, int N) {
    __shared__ int deg[CHUNK];
    __shared__ int lofs[CHUNK];
    __shared__ int cur[CHUNK];
    int b = blockIdx.x, tid = threadIdx.x;
    if (tid < CHUNK) deg[tid] = 0;
    __syncthreads();
    int cnt = cursorG[b]; if (cnt > CAP) cnt = CAP;
    const size_t tb = (size_t)b * CAP;
    for (int i = tid; i < cnt; i += 256) atomicAdd(&deg[temp[tb + i] >> 17], 1);
    __syncthreads();
    if (tid < CHUNK) lofs[tid] = deg[tid];
    __syncthreads();
#pragma unroll
    for (int off = 1; off < CHUNK; off <<= 1) {
        int t = (tid < CHUNK && tid >= off) ? lofs[tid - off] : 0;
        __syncthreads();
        if (tid < CHUNK) lofs[tid] += t;
        __syncthreads();
    }
    int base = bucketBase[b];
    if (tid < CHUNK) {
        int excl = lofs[tid] - deg[tid];
        lofs[tid] = excl;
        cur[tid] = 0;
        int node = b * CHUNK + tid;
        if (node < N) {
            row_ptr[node] = base + excl;
            dinv[node] = rsqrtf((float)deg[tid] + 1.0f);
        }
    }
    __syncthreads();
    for (int i = tid; i < cnt; i += 256) {
        unsigned int p = temp[tb + i];
        int dl = p >> 17;
        int rank = atomicAdd(&cur[dl], 1);
        csr_src[base + lofs[dl] + rank] = (int)(p & 0x1FFFFu);
    }
}

// Wt[n][k] = bf16(W[k][n])  (64x64, one block)
__global__ void k_prepW(const float* __restrict__ W, unsigned short* __restrict__ Wt) {
    for (int i = threadIdx.x; i < 64 * 64; i += 256) {
        int n = i >> 6, k = i & 63;
        Wt[i] = f2bf(W[k * 64 + n]);
    }
}

// Shared MFMA body: A-fragments provided by caller; B from Wt; store bf16 Hs.
__device__ __forceinline__ void mfma_tail(short8 a0, short8 a1,
                                          const unsigned short* __restrict__ Wt,
                                          unsigned short* __restrict__ Hs,
                                          int row0, int r, int q, int N) {
    short8 bfrag[4][2];
#pragma unroll
    for (int ct = 0; ct < 4; ++ct)
#pragma unroll
        for (int kb = 0; kb < 2; ++kb)
            bfrag[ct][kb] = *(const short8*)(Wt + (ct * 16 + r) * 64 + q * 8 + 32 * kb);
    f32x4 acc[4];
#pragma unroll
    for (int ct = 0; ct < 4; ++ct) {
        acc[ct] = (f32x4){0.0f, 0.0f, 0.0f, 0.0f};
        acc[ct] = __builtin_amdgcn_mfma_f32_16x16x32_bf16(a0, bfrag[ct][0], acc[ct], 0, 0, 0);
        acc[ct] = __builtin_amdgcn_mfma_f32_16x16x32_bf16(a1, bfrag[ct][1], acc[ct], 0, 0, 0);
    }
#pragma unroll
    for (int reg = 0; reg < 4; ++reg) {
        int row = row0 + q * 4 + reg;
        if (row < N) {
            size_t base = (size_t)row * 64 + r;
#pragma unroll
            for (int ct = 0; ct < 4; ++ct)
                Hs[base + ct * 16] = f2bf(acc[ct][reg]);
        }
    }
}

// GEMM1: fp32 X in, dinv folded into A-fragment conversion.
__global__ __launch_bounds__(256) void k_gemm_mfma_x(const float* __restrict__ X,
                                                     const float* __restrict__ dinv,
                                                     const unsigned short* __restrict__ Wt,
                                                     unsigned short* __restrict__ Hs,
                                                     int nTiles, int N) {
    int wave = threadIdx.x >> 6, lane = threadIdx.x & 63;
    int tile = blockIdx.x * 4 + wave;
    if (tile >= nTiles) return;
    int r = lane & 15, q = lane >> 4;
    int row0 = tile * 16;
    int row = row0 + r;
    int rr = row < N ? row : N - 1;
    float d = dinv[rr];
    const float* xrow = X + (size_t)rr * 64 + q * 8;
    short8 a0, a1;
#pragma unroll
    for (int j = 0; j < 8; ++j) a0[j] = (short)f2bf(xrow[j] * d);
#pragma unroll
    for (int j = 0; j < 8; ++j) a1[j] = (short)f2bf(xrow[32 + j] * d);
    mfma_tail(a0, a1, Wt, Hs, row0, r, q, N);
}

// GEMM2: bf16 Ab in (already dinv-scaled by aggregate1).
__global__ __launch_bounds__(256) void k_gemm_mfma(const unsigned short* __restrict__ Xb,
                                                   const unsigned short* __restrict__ Wt,
                                                   unsigned short* __restrict__ Hs,
                                                   int nTiles, int N) {
    int wave = threadIdx.x >> 6, lane = threadIdx.x & 63;
    int tile = blockIdx.x * 4 + wave;
    if (tile >= nTiles) return;
    int r = lane & 15, q = lane >> 4;
    int row0 = tile * 16;
    const unsigned short* xrow = Xb + (size_t)(row0 + r) * 64 + q * 8;
    short8 a0 = *(const short8*)(xrow);
    short8 a1 = *(const short8*)(xrow + 32);
    mfma_tail(a0, a1, Wt, Hs, row0, r, q, N);
}

// Multi-row gather: wave = 8 groups x 8 lanes; group g gathers edge t+g's
// src row at 16B/lane (ushort8) -> one VMEM instruction covers 8 edges.
// All __shfl ops exec-uniform; only the consuming gather/add is predicated.
__device__ __forceinline__ void agg_node8(const unsigned short* __restrict__ Hs,
                                          const int* __restrict__ csr_src,
                                          int beg, int end, int lane, float* a) {
    int g = lane >> 3, s = lane & 7;
    for (int base = beg; base < end; base += 64) {
        int m = end - base; if (m > 64) m = 64;
        int idx = (lane < m) ? csr_src[base + lane] : 0;   // coalesced
        int t = 0;
        for (; t + 16 <= m; t += 16) {                     // 2 gathers in flight
            int s0 = __shfl(idx, t + g, 64);
            int s1 = __shfl(idx, t + 8 + g, 64);
            ushort8 h0 = *(const ushort8*)(Hs + (size_t)s0 * 64 + s * 8);
            ushort8 h1 = *(const ushort8*)(Hs + (size_t)s1 * 64 + s * 8);
#pragma unroll
            for (int j = 0; j < 8; ++j) a[j] += bf2f(h0[j]) + bf2f(h1[j]);
        }
        for (; t + 8 <= m; t += 8) {
            int s0 = __shfl(idx, t + g, 64);
            ushort8 h0 = *(const ushort8*)(Hs + (size_t)s0 * 64 + s * 8);
#pragma unroll
            for (int j = 0; j < 8; ++j) a[j] += bf2f(h0[j]);
        }
        int rem = m - t;
        if (rem > 0) {                    // wave-uniform guard
            int sl = t + ((g < rem) ? g : 0);   // shfl exec-uniform, clamped src
            int s0 = __shfl(idx, sl, 64);
            if (g < rem) {                // divergent CONSUMER only
                ushort8 h0 = *(const ushort8*)(Hs + (size_t)s0 * 64 + s * 8);
#pragma unroll
                for (int j = 0; j < 8; ++j) a[j] += bf2f(h0[j]);
            }
        }
    }
    // cross-group butterfly (bits 3,4,5): exec-uniform
#pragma unroll
    for (int j = 0; j < 8; ++j) {
        a[j] += __shfl_xor(a[j], 8, 64);
        a[j] += __shfl_xor(a[j], 16, 64);
        a[j] += __shfl_xor(a[j], 32, 64);
    }
}

// layer-1: Ab[d, f] = bf16( dinv[d] * relu(b[f] + dinv[d] * agg) )
__global__ __launch_bounds__(256) void k_aggregate1(const unsigned short* __restrict__ Hs,
                                                    const int* __restrict__ csr_src,
                                                    const int* __restrict__ row_ptr,
                                                    const float* __restrict__ dinv,
                                                    const float* __restrict__ bias,
                                                    unsigned short* __restrict__ Ab, int n) {
    int wave = threadIdx.x >> 6, lane = threadIdx.x & 63;
    int node = blockIdx.x * 4 + wave;
    if (node >= n) return;
    int beg = __builtin_amdgcn_readfirstlane(row_ptr[node]);
    int end = __builtin_amdgcn_readfirstlane(row_ptr[node + 1]);
    float a[8] = {0.f, 0.f, 0.f, 0.f, 0.f, 0.f, 0.f, 0.f};
    agg_node8(Hs, csr_src, beg, end, lane, a);
    if ((lane >> 3) == 0) {          // lanes 0..7 hold the result (8 chans each)
        int s = lane;
        ushort8 hs = *(const ushort8*)(Hs + (size_t)node * 64 + s * 8);
        float d = dinv[node];
        ushort8 o;
#pragma unroll
        for (int j = 0; j < 8; ++j) {
            float v = fmaxf(bias[s * 8 + j] + d * (a[j] + bf2f(hs[j])), 0.0f);
            o[j] = f2bf(v * d);
        }
        *(ushort8*)(Ab + (size_t)node * 64 + s * 8) = o;
    }
}

// layer-2: block-reduce 4 relu'd rows -> P[block, f]  (A never materialized)
__global__ __launch_bounds__(256) void k_aggregate2(const unsigned short* __restrict__ Hs,
                                                    const int* __restrict__ csr_src,
                                                    const int* __restrict__ row_ptr,
                                                    const float* __restrict__ dinv,
                                                    const float* __restrict__ bias,
                                                    float* __restrict__ P, int n) {
    __shared__ float red[256];
    int wave = threadIdx.x >> 6, lane = threadIdx.x & 63;
    int node = blockIdx.x * 4 + wave;
    bool active = node < n;
    int nn = active ? node : (n - 1);
    int beg = __builtin_amdgcn_readfirstlane(row_ptr[nn]);
    int end = __builtin_amdgcn_readfirstlane(row_ptr[nn + 1]);
    if (!active) { beg = 0; end = 0; }
    float a[8] = {0.f, 0.f, 0.f, 0.f, 0.f, 0.f, 0.f, 0.f};
    agg_node8(Hs, csr_src, beg, end, lane, a);
    if ((lane >> 3) == 0) {
        int s = lane;
        float v[8];
#pragma unroll
        for (int j = 0; j < 8; ++j) v[j] = 0.0f;
        if (active) {
            ushort8 hs = *(const ushort8*)(Hs + (size_t)node * 64 + s * 8);
            float d = dinv[node];
#pragma unroll
            for (int j = 0; j < 8; ++j)
                v[j] = fmaxf(bias[s * 8 + j] + d * (a[j] + bf2f(hs[j])), 0.0f);
        }
#pragma unroll
        for (int j = 0; j < 8; ++j) red[wave * 64 + s * 8 + j] = v[j];
    }
    __syncthreads();
    if (threadIdx.x < 64)
        P[(size_t)blockIdx.x * 64 + threadIdx.x] =
            red[threadIdx.x] + red[64 + threadIdx.x] +
            red[128 + threadIdx.x] + red[192 + threadIdx.x];
}

__global__ void k_zero64(float* __restrict__ S) {
    if (threadIdx.x < 64) S[threadIdx.x] = 0.0f;
}

__global__ void k_colsum(const float* __restrict__ P, float* __restrict__ S, int rows) {
    int f = threadIdx.x;
    float acc = 0.0f;
    for (int r = blockIdx.x; r < rows; r += gridDim.x) acc += P[r * 64 + f];
    atomicAdd(&S[f], acc);
}

__global__ void k_fc(const float* __restrict__ S, const float* __restrict__ fcw,
                     const float* __restrict__ fcb, float* __restrict__ out, int n) {
    int j = threadIdx.x;
    float inv = 1.0f / (float)n;
    float acc = fcb[j];
#pragma unroll
    for (int k = 0; k < 64; ++k) acc += (S[k] * inv) * fcw[j * 64 + k];
    out[j] = acc;
}

extern "C" void kernel_launch(void* const* d_in, const int* in_sizes, int n_in,
                              void* d_out, int out_size, void* d_ws, size_t ws_size,
                              hipStream_t stream) {
    const float* x[2]  = {(const float*)d_in[0], (const float*)d_in[1]};
    const int*   ei[2] = {(const int*)d_in[2], (const int*)d_in[3]};
    const float* W1  = (const float*)d_in[4];
    const float* b1  = (const float*)d_in[5];
    const float* W2  = (const float*)d_in[6];
    const float* b2  = (const float*)d_in[7];
    const float* fcw = (const float*)d_in[8];
    const float* fcb = (const float*)d_in[9];
    float* out = (float*)d_out;

    const int N  = in_sizes[0] / 64;
    const int E  = in_sizes[2] / 2;
    const int NF = N * 64;
    const int K  = (N + CHUNK - 1) / CHUNK;     // 782 buckets
    const int gGm = (N + 3) / 4;                // aggregate blocks (4 nodes each)
    const int nTiles = (N + 15) / 16;           // gemm row-tiles

    char* w = (char*)d_ws;
    size_t off = 0;
    auto alloc = [&](size_t bytes) { void* p = w + off; off += (bytes + 127) & ~127ull; return p; };
    unsigned int* temp   = (unsigned int*)alloc((size_t)K * CAP * 4);      // 12.8 MB
    unsigned short* Ab   = (unsigned short*)alloc(((size_t)NF + 1024) * 2);
    unsigned short* Hs   = (unsigned short*)alloc((size_t)NF * 2);
    int*   csr_src       = (int*)alloc((size_t)E * 4);
    int*   row_ptr       = (int*)alloc((size_t)(N + 1) * 4);
    float* dinv          = (float*)alloc((size_t)N * 4);
    int*   cursorG       = (int*)alloc((size_t)K * 4);
    int*   bucketBase    = (int*)alloc((size_t)K * 4);
    float* P             = (float*)alloc((size_t)gGm * 64 * 4);
    float* S             = (float*)alloc(64 * 4);
    unsigned short* Wt1  = (unsigned short*)alloc(64 * 64 * 2);
    unsigned short* Wt2  = (unsigned short*)alloc(64 * 64 * 2);

    const int gBin = (E + EPB - 1) / EPB;
    const int gK   = (K + TPB - 1) / TPB;
    const int gMf  = (nTiles + 3) / 4;

    // weights shared across both graphs -- prep once
    k_prepW<<<1, 256, 0, stream>>>(W1, Wt1);
    k_prepW<<<1, 256, 0, stream>>>(W2, Wt2);

    for (int g = 0; g < 2; ++g) {
        const int* esrc = ei[g];
        const int* edst = ei[g] + E;

        // bucketed CSR build (+ dinv fused)
        k_zero_int<<<gK, TPB, 0, stream>>>(cursorG, K);
        k_binA<<<gBin, 256, 0, stream>>>(esrc, edst, cursorG, temp, E, K);
        k_scanK<<<1, 1024, 0, stream>>>(cursorG, bucketBase, row_ptr, K, N, E);
        k_csr_bucket<<<K, 256, 0, stream>>>(temp, cursorG, bucketBase,
                                            csr_src, row_ptr, dinv, N);

        // layer 1 (castX fused into gemm)
        k_gemm_mfma_x<<<gMf, 256, 0, stream>>>(x[g], dinv, Wt1, Hs, nTiles, N);
        k_aggregate1<<<gGm, TPB, 0, stream>>>(Hs, csr_src, row_ptr, dinv, b1, Ab, N);

        // layer 2
        k_gemm_mfma<<<gMf, 256, 0, stream>>>(Ab, Wt2, Hs, nTiles, N);
        k_aggregate2<<<gGm, TPB, 0, stream>>>(Hs, csr_src, row_ptr, dinv, b2, P, N);

        // mean-pool + FC
        k_zero64<<<1, 64, 0, stream>>>(S);
        k_colsum<<<256, 64, 0, stream>>>(P, S, gGm);
        k_fc<<<1, 64, 0, stream>>>(S, fcw, fcb, out + g * 64, N);
    }
}

// Round 11
// 430.341 us; speedup vs baseline: 7.4034x; 1.1607x over previous
//
#include <hip/hip_runtime.h>

// SiameseGNN round 11: both graphs batched per dispatch + packed-fp32 aggregate.
//
// R10 evidence: aggregate now VALU-bound (VALUBusy 62%, FETCH 85MB flat) --
// ~100 VALU/node from per-channel bf16 unpack+add and butterfly. CSR phase
// (binA/scanK/csr_bucket ~110us across graphs) is occupancy-starved and the
// two graphs serialize across 20 dispatches.
// Fixes:
//   1. Ctx-based batching: every kernel takes (ctx0, ctx1, nb0) and serves
//      both graphs in one dispatch (blockIdx split). ws_size guard: if
//      scratch < 2 buffer sets (~80MB), fall back to sequential (1 set).
//   2. Aggregate accumulates float2 pairs -> v_pk_add_f32 (1 add / 2 chans);
//      butterfly adds packed too.
//   3. Pool fused: colsum -> per-block partials (no atomics/zero64), FC
//      reduces partials in one wave. prepW merged into one dispatch.

#define TPB    256
#define CHUNK  128
#define SHIFT  7
#define KMAX   1024
#define CAP    2560     // mean 2046, sigma ~45 -> mean+11sigma, was 4096
#define EPB    4096

typedef __attribute__((ext_vector_type(8))) short short8;
typedef __attribute__((ext_vector_type(8))) unsigned short ushort8;
typedef __attribute__((ext_vector_type(4))) float f32x4;
typedef __attribute__((ext_vector_type(2))) float float2v;

struct Ctx {
    const float* X; const int* esrc; const int* edst;
    unsigned int* temp; unsigned short* Ab; unsigned short* Hs;
    int* csr; int* row_ptr; float* dinv; int* cursorG; int* bucketBase;
    float* P; float* P2; float* outp;
};

__device__ __forceinline__ float bf2f(unsigned short u) {
    union { unsigned int i; float f; } c; c.i = ((unsigned int)u) << 16; return c.f;
}
__device__ __forceinline__ unsigned short f2bf(float x) {
    union { float f; unsigned int i; } c; c.f = x;
    unsigned int r = c.i + 0x7FFFu + ((c.i >> 16) & 1u);   // RNE
    return (unsigned short)(r >> 16);
}
// unpack bf16 pair (one dword) -> float2 {low, high}
__device__ __forceinline__ float2v up2(unsigned int w) {
    union { unsigned int i; float f; } lo, hi;
    lo.i = w << 16; hi.i = w & 0xFFFF0000u;
    float2v r; r.x = lo.f; r.y = hi.f; return r;
}

__global__ void k_prepW2(const float* __restrict__ W1, const float* __restrict__ W2,
                         unsigned short* __restrict__ Wt1, unsigned short* __restrict__ Wt2) {
    const float* W = blockIdx.x ? W2 : W1;
    unsigned short* Wt = blockIdx.x ? Wt2 : Wt1;
    for (int i = threadIdx.x; i < 64 * 64; i += 256) {
        int n = i >> 6, k = i & 63;
        Wt[i] = f2bf(W[k * 64 + n]);
    }
}

__global__ void k_zeroCur(Ctx c0, Ctx c1, int nb0, int K) {
    int b = blockIdx.x; Ctx c = c0;
    if (b >= nb0) { c = c1; b -= nb0; }
    int i = b * blockDim.x + threadIdx.x;
    if (i < K) c.cursorG[i] = 0;
}

// Bucket edges by dst (packed (dstLocal<<17)|src) -- contiguous segment writes.
__global__ __launch_bounds__(256) void k_binA(Ctx c0, Ctx c1, int nb0, int E, int K) {
    __shared__ int cnt[KMAX];
    __shared__ int segBase[KMAX];
    int b = blockIdx.x; Ctx c = c0;
    if (b >= nb0) { c = c1; b -= nb0; }
    int tid = threadIdx.x;
    for (int j = tid; j < K; j += 256) cnt[j] = 0;
    __syncthreads();
    int base = b * EPB;
#pragma unroll
    for (int k = 0; k < EPB / 256; ++k) {
        int e = base + k * 256 + tid;
        if (e < E) atomicAdd(&cnt[c.edst[e] >> SHIFT], 1);
    }
    __syncthreads();
    for (int j = tid; j < K; j += 256) {
        int cc = cnt[j];
        segBase[j] = cc ? atomicAdd(&c.cursorG[j], cc) : 0;
        cnt[j] = 0;
    }
    __syncthreads();
#pragma unroll
    for (int k = 0; k < EPB / 256; ++k) {
        int e = base + k * 256 + tid;
        if (e < E) {
            int d = c.edst[e];
            int bk = d >> SHIFT;
            int pos = segBase[bk] + atomicAdd(&cnt[bk], 1);
            if (pos < CAP)
                c.temp[(size_t)bk * CAP + pos] =
                    ((unsigned int)(d & (CHUNK - 1)) << 17) | (unsigned int)c.esrc[e];
        }
    }
}

__global__ __launch_bounds__(1024) void k_scanK(Ctx c0, Ctx c1, int K, int N, int E) {
    Ctx c = blockIdx.x ? c1 : c0;
    __shared__ int s[1024];
    int tid = threadIdx.x;
    int v = (tid < K) ? c.cursorG[tid] : 0;
    s[tid] = v;
    __syncthreads();
#pragma unroll
    for (int off = 1; off < 1024; off <<= 1) {
        int t = (tid >= off) ? s[tid - off] : 0;
        __syncthreads();
        s[tid] += t;
        __syncthreads();
    }
    if (tid < K) c.bucketBase[tid] = s[tid] - v;
    if (tid == 0) c.row_ptr[N] = E;
}

// Per-bucket LDS counting sort -> contiguous csr slice + row_ptr + dinv.
__global__ __launch_bounds__(256) void k_csrb(Ctx c0, Ctx c1, int nb0, int N) {
    __shared__ int deg[CHUNK];
    __shared__ int lofs[CHUNK];
    __shared__ int cur[CHUNK];
    int b = blockIdx.x; Ctx c = c0;
    if (b >= nb0) { c = c1; b -= nb0; }
    int tid = threadIdx.x;
    if (tid < CHUNK) deg[tid] = 0;
    __syncthreads();
    int cnt = c.cursorG[b]; if (cnt > CAP) cnt = CAP;
    const size_t tb = (size_t)b * CAP;
    for (int i = tid; i < cnt; i += 256) atomicAdd(&deg[c.temp[tb + i] >> 17], 1);
    __syncthreads();
    if (tid < CHUNK) lofs[tid] = deg[tid];
    __syncthreads();
#pragma unroll
    for (int off = 1; off < CHUNK; off <<= 1) {
        int t = (tid < CHUNK && tid >= off) ? lofs[tid - off] : 0;
        __syncthreads();
        if (tid < CHUNK) lofs[tid] += t;
        __syncthreads();
    }
    int base = c.bucketBase[b];
    if (tid < CHUNK) {
        int excl = lofs[tid] - deg[tid];
        lofs[tid] = excl;
        cur[tid] = 0;
        int node = b * CHUNK + tid;
        if (node < N) {
            c.row_ptr[node] = base + excl;
            c.dinv[node] = rsqrtf((float)deg[tid] + 1.0f);
        }
    }
    __syncthreads();
    for (int i = tid; i < cnt; i += 256) {
        unsigned int p = c.temp[tb + i];
        int dl = p >> 17;
        int rank = atomicAdd(&cur[dl], 1);
        c.csr[base + lofs[dl] + rank] = (int)(p & 0x1FFFFu);
    }
}

// Shared MFMA body: A-fragments provided; B from Wt; store bf16 Hs.
__device__ __forceinline__ void mfma_tail(short8 a0, short8 a1,
                                          const unsigned short* __restrict__ Wt,
                                          unsigned short* __restrict__ Hs,
                                          int row0, int r, int q, int N) {
    short8 bfrag[4][2];
#pragma unroll
    for (int ct = 0; ct < 4; ++ct)
#pragma unroll
        for (int kb = 0; kb < 2; ++kb)
            bfrag[ct][kb] = *(const short8*)(Wt + (ct * 16 + r) * 64 + q * 8 + 32 * kb);
    f32x4 acc[4];
#pragma unroll
    for (int ct = 0; ct < 4; ++ct) {
        acc[ct] = (f32x4){0.0f, 0.0f, 0.0f, 0.0f};
        acc[ct] = __builtin_amdgcn_mfma_f32_16x16x32_bf16(a0, bfrag[ct][0], acc[ct], 0, 0, 0);
        acc[ct] = __builtin_amdgcn_mfma_f32_16x16x32_bf16(a1, bfrag[ct][1], acc[ct], 0, 0, 0);
    }
#pragma unroll
    for (int reg = 0; reg < 4; ++reg) {
        int row = row0 + q * 4 + reg;
        if (row < N) {
            size_t base = (size_t)row * 64 + r;
#pragma unroll
            for (int ct = 0; ct < 4; ++ct)
                Hs[base + ct * 16] = f2bf(acc[ct][reg]);
        }
    }
}

// GEMM1: fp32 X in, dinv folded into A-fragment conversion.
__global__ __launch_bounds__(256) void k_gemm1(Ctx c0, Ctx c1, int nb0,
                                               const unsigned short* __restrict__ Wt,
                                               int nTiles, int N) {
    int b = blockIdx.x; Ctx c = c0;
    if (b >= nb0) { c = c1; b -= nb0; }
    int wave = threadIdx.x >> 6, lane = threadIdx.x & 63;
    int tile = b * 4 + wave;
    if (tile >= nTiles) return;
    int r = lane & 15, q = lane >> 4;
    int row0 = tile * 16;
    int row = row0 + r;
    int rr = row < N ? row : N - 1;
    float d = c.dinv[rr];
    const float* xrow = c.X + (size_t)rr * 64 + q * 8;
    short8 a0, a1;
#pragma unroll
    for (int j = 0; j < 8; ++j) a0[j] = (short)f2bf(xrow[j] * d);
#pragma unroll
    for (int j = 0; j < 8; ++j) a1[j] = (short)f2bf(xrow[32 + j] * d);
    mfma_tail(a0, a1, Wt, c.Hs, row0, r, q, N);
}

// GEMM2: bf16 Ab in (already dinv-scaled by aggregate1).
__global__ __launch_bounds__(256) void k_gemm2(Ctx c0, Ctx c1, int nb0,
                                               const unsigned short* __restrict__ Wt,
                                               int nTiles, int N) {
    int b = blockIdx.x; Ctx c = c0;
    if (b >= nb0) { c = c1; b -= nb0; }
    int wave = threadIdx.x >> 6, lane = threadIdx.x & 63;
    int tile = b * 4 + wave;
    if (tile >= nTiles) return;
    int r = lane & 15, q = lane >> 4;
    int row0 = tile * 16;
    const unsigned short* xrow = c.Ab + (size_t)(row0 + r) * 64 + q * 8;
    short8 a0 = *(const short8*)(xrow);
    short8 a1 = *(const short8*)(xrow + 32);
    mfma_tail(a0, a1, Wt, c.Hs, row0, r, q, N);
}

// 8 groups x 8 lanes, uint4 (16B) per lane = one VMEM inst per 8 edges.
// Channels accumulated as float2 pairs -> v_pk_add_f32. All shfls
// exec-uniform; only the consuming gather/add predicated.
__device__ __forceinline__ void agg_node8(const unsigned short* __restrict__ Hs,
                                          const int* __restrict__ csr,
                                          int beg, int end, int lane, float2v* acc) {
    int g = lane >> 3, s = lane & 7;
    for (int base = beg; base < end; base += 64) {
        int m = end - base; if (m > 64) m = 64;
        int idx = (lane < m) ? csr[base + lane] : 0;   // coalesced
        int t = 0;
        for (; t + 16 <= m; t += 16) {                 // 2 gathers in flight
            int s0 = __shfl(idx, t + g, 64);
            int s1 = __shfl(idx, t + 8 + g, 64);
            uint4 h0 = *(const uint4*)(Hs + (size_t)s0 * 64 + s * 8);
            uint4 h1 = *(const uint4*)(Hs + (size_t)s1 * 64 + s * 8);
            acc[0] += up2(h0.x); acc[1] += up2(h0.y);
            acc[2] += up2(h0.z); acc[3] += up2(h0.w);
            acc[0] += up2(h1.x); acc[1] += up2(h1.y);
            acc[2] += up2(h1.z); acc[3] += up2(h1.w);
        }
        for (; t + 8 <= m; t += 8) {
            int s0 = __shfl(idx, t + g, 64);
            uint4 h0 = *(const uint4*)(Hs + (size_t)s0 * 64 + s * 8);
            acc[0] += up2(h0.x); acc[1] += up2(h0.y);
            acc[2] += up2(h0.z); acc[3] += up2(h0.w);
        }
        int rem = m - t;
        if (rem > 0) {                     // wave-uniform guard
            int sl = t + ((g < rem) ? g : 0);   // shfl exec-uniform, clamped src
            int s0 = __shfl(idx, sl, 64);
            if (g < rem) {                 // divergent CONSUMER only
                uint4 h0 = *(const uint4*)(Hs + (size_t)s0 * 64 + s * 8);
                acc[0] += up2(h0.x); acc[1] += up2(h0.y);
                acc[2] += up2(h0.z); acc[3] += up2(h0.w);
            }
        }
    }
    // cross-group butterfly (bits 3,4,5): exec-uniform, packed adds
#pragma unroll
    for (int k = 0; k < 4; ++k) {
        float2v o;
        o.x = __shfl_xor(acc[k].x, 8, 64);  o.y = __shfl_xor(acc[k].y, 8, 64);  acc[k] += o;
        o.x = __shfl_xor(acc[k].x, 16, 64); o.y = __shfl_xor(acc[k].y, 16, 64); acc[k] += o;
        o.x = __shfl_xor(acc[k].x, 32, 64); o.y = __shfl_xor(acc[k].y, 32, 64); acc[k] += o;
    }
}

// layer-1: Ab[d, f] = bf16( dinv[d] * relu(b[f] + dinv[d] * agg) )
__global__ __launch_bounds__(256) void k_agg1(Ctx c0, Ctx c1, int nb0,
                                              const float* __restrict__ bias, int n) {
    int b = blockIdx.x; Ctx c = c0;
    if (b >= nb0) { c = c1; b -= nb0; }
    int wave = threadIdx.x >> 6, lane = threadIdx.x & 63;
    int node = b * 4 + wave;
    if (node >= n) return;
    int beg = __builtin_amdgcn_readfirstlane(c.row_ptr[node]);
    int end = __builtin_amdgcn_readfirstlane(c.row_ptr[node + 1]);
    float2v acc[4];
#pragma unroll
    for (int k = 0; k < 4; ++k) acc[k] = (float2v){0.f, 0.f};
    agg_node8(c.Hs, c.csr, beg, end, lane, acc);
    if ((lane >> 3) == 0) {          // lanes 0..7 hold results (8 chans each)
        int s = lane;
        uint4 hsv = *(const uint4*)(c.Hs + (size_t)node * 64 + s * 8);
        unsigned int hsd[4] = {hsv.x, hsv.y, hsv.z, hsv.w};
        float d = c.dinv[node];
        ushort8 o;
#pragma unroll
        for (int k = 0; k < 4; ++k) {
            float2v hv = up2(hsd[k]);
            float v0 = fmaxf(bias[s * 8 + 2 * k]     + d * (acc[k].x + hv.x), 0.0f) * d;
            float v1 = fmaxf(bias[s * 8 + 2 * k + 1] + d * (acc[k].y + hv.y), 0.0f) * d;
            o[2 * k] = (short)f2bf(v0); o[2 * k + 1] = (short)f2bf(v1);
        }
        *(ushort8*)(c.Ab + (size_t)node * 64 + s * 8) = o;
    }
}

// layer-2: block-reduce 4 relu'd rows -> P[block, f]  (A never materialized)
__global__ __launch_bounds__(256) void k_agg2(Ctx c0, Ctx c1, int nb0,
                                              const float* __restrict__ bias, int n) {
    __shared__ float red[256];
    int b = blockIdx.x; Ctx c = c0;
    if (b >= nb0) { c = c1; b -= nb0; }
    int wave = threadIdx.x >> 6, lane = threadIdx.x & 63;
    int node = b * 4 + wave;
    bool active = node < n;
    int nn = active ? node : (n - 1);
    int beg = __builtin_amdgcn_readfirstlane(c.row_ptr[nn]);
    int end = __builtin_amdgcn_readfirstlane(c.row_ptr[nn + 1]);
    if (!active) { beg = 0; end = 0; }
    float2v acc[4];
#pragma unroll
    for (int k = 0; k < 4; ++k) acc[k] = (float2v){0.f, 0.f};
    agg_node8(c.Hs, c.csr, beg, end, lane, acc);
    if ((lane >> 3) == 0) {
        int s = lane;
        float v[8];
#pragma unroll
        for (int j = 0; j < 8; ++j) v[j] = 0.0f;
        if (active) {
            uint4 hsv = *(const uint4*)(c.Hs + (size_t)node * 64 + s * 8);
            unsigned int hsd[4] = {hsv.x, hsv.y, hsv.z, hsv.w};
            float d = c.dinv[node];
#pragma unroll
            for (int k = 0; k < 4; ++k) {
                float2v hv = up2(hsd[k]);
                v[2 * k]     = fmaxf(bias[s * 8 + 2 * k]     + d * (acc[k].x + hv.x), 0.0f);
                v[2 * k + 1] = fmaxf(bias[s * 8 + 2 * k + 1] + d * (acc[k].y + hv.y), 0.0f);
            }
        }
#pragma unroll
        for (int j = 0; j < 8; ++j) red[wave * 64 + s * 8 + j] = v[j];
    }
    __syncthreads();
    if (threadIdx.x < 64)
        c.P[(size_t)b * 64 + threadIdx.x] =
            red[threadIdx.x] + red[64 + threadIdx.x] +
            red[128 + threadIdx.x] + red[192 + threadIdx.x];
}

// colsum -> per-block partials in P2 (no atomics, no zero pass)
__global__ void k_colsum(Ctx c0, Ctx c1, int nb0, int rows) {
    int b = blockIdx.x; Ctx c = c0;
    if (b >= nb0) { c = c1; b -= nb0; }
    int f = threadIdx.x;  // 64
    float acc = 0.0f;
    for (int r = b; r < rows; r += nb0) acc += c.P[(size_t)r * 64 + f];
    c.P2[b * 64 + f] = acc;
}

// single-wave FC: reduce 256 partial rows, then out = fcb + (S/n) @ fcw^T
__global__ void k_fc(Ctx c0, Ctx c1, const float* __restrict__ fcw,
                     const float* __restrict__ fcb, int n) {
    Ctx c = blockIdx.x ? c1 : c0;
    __shared__ float S[64];
    int j = threadIdx.x;  // 64
    float s = 0.0f;
    for (int r = 0; r < 256; ++r) s += c.P2[r * 64 + j];
    S[j] = s;
    __syncthreads();
    float inv = 1.0f / (float)n;
    float acc = fcb[j];
#pragma unroll
    for (int k = 0; k < 64; ++k) acc += (S[k] * inv) * fcw[j * 64 + k];
    c.outp[j] = acc;
}

extern "C" void kernel_launch(void* const* d_in, const int* in_sizes, int n_in,
                              void* d_out, int out_size, void* d_ws, size_t ws_size,
                              hipStream_t stream) {
    const float* x[2]  = {(const float*)d_in[0], (const float*)d_in[1]};
    const int*   ei[2] = {(const int*)d_in[2], (const int*)d_in[3]};
    const float* W1  = (const float*)d_in[4];
    const float* b1  = (const float*)d_in[5];
    const float* W2  = (const float*)d_in[6];
    const float* b2  = (const float*)d_in[7];
    const float* fcw = (const float*)d_in[8];
    const float* fcb = (const float*)d_in[9];
    float* out = (float*)d_out;

    const int N  = in_sizes[0] / 64;
    const int E  = in_sizes[2] / 2;
    const int NF = N * 64;
    const int K  = (N + CHUNK - 1) / CHUNK;     // 782 buckets
    const int gGm = (N + 3) / 4;                // aggregate blocks
    const int nTiles = (N + 15) / 16;
    const int gMf = (nTiles + 3) / 4;
    const int gBin = (E + EPB - 1) / EPB;
    const int gK  = (K + TPB - 1) / TPB;

    auto al = [](size_t x) { return (x + 127) & ~(size_t)127; };
    size_t tempB = (size_t)K * CAP * 4;          // 8.0 MB
    size_t abB   = ((size_t)NF + 64) * 2;        // 12.8 MB
    size_t szRegion = al(tempB > abB ? tempB : abB);   // Ab aliases temp
    size_t szHs  = al((size_t)NF * 2);
    size_t szCsr = al((size_t)E * 4);
    size_t szRp  = al((size_t)(N + 1) * 4);
    size_t szDi  = al((size_t)N * 4);
    size_t szCu  = al((size_t)K * 4);
    size_t szBB  = al((size_t)K * 4);
    size_t szP   = al((size_t)gGm * 64 * 4);
    size_t szP2  = al((size_t)256 * 64 * 4);
    size_t setB  = szRegion + szHs + szCsr + szRp + szDi + szCu + szBB + szP + szP2;
    size_t wtB   = 2 * al(64 * 64 * 2);
    bool batched = ws_size >= wtB + 2 * setB;

    char* base = (char*)d_ws;
    unsigned short* Wt1 = (unsigned short*)base;
    unsigned short* Wt2 = (unsigned short*)(base + al(64 * 64 * 2));

    auto mkctx = [&](int g, char* p) {
        Ctx c;
        c.X = x[g]; c.esrc = ei[g]; c.edst = ei[g] + E;
        c.temp = (unsigned int*)p; c.Ab = (unsigned short*)p; p += szRegion;
        c.Hs = (unsigned short*)p; p += szHs;
        c.csr = (int*)p; p += szCsr;
        c.row_ptr = (int*)p; p += szRp;
        c.dinv = (float*)p; p += szDi;
        c.cursorG = (int*)p; p += szCu;
        c.bucketBase = (int*)p; p += szBB;
        c.P = (float*)p; p += szP;
        c.P2 = (float*)p;
        c.outp = out + g * 64;
        return c;
    };
    char* set0 = base + wtB;
    Ctx c0 = mkctx(0, set0);
    Ctx c1 = mkctx(1, batched ? set0 + setB : set0);   // fallback: shares set0

    k_prepW2<<<2, 256, 0, stream>>>(W1, W2, Wt1, Wt2);

    auto pipe = [&](Ctx A, Ctx B, int mult) {
        k_zeroCur<<<mult * gK, TPB, 0, stream>>>(A, B, gK, K);
        k_binA<<<mult * gBin, 256, 0, stream>>>(A, B, gBin, E, K);
        k_scanK<<<mult, 1024, 0, stream>>>(A, B, K, N, E);
        k_csrb<<<mult * K, 256, 0, stream>>>(A, B, K, N);
        k_gemm1<<<mult * gMf, 256, 0, stream>>>(A, B, gMf, Wt1, nTiles, N);
        k_agg1<<<mult * gGm, 256, 0, stream>>>(A, B, gGm, b1, N);
        k_gemm2<<<mult * gMf, 256, 0, stream>>>(A, B, gMf, Wt2, nTiles, N);
        k_agg2<<<mult * gGm, 256, 0, stream>>>(A, B, gGm, b2, N);
        k_colsum<<<mult * 256, 64, 0, stream>>>(A, B, 256, gGm);
        k_fc<<<mult, 64, 0, stream>>>(A, B, fcw, fcb, N);
    };

    if (batched) {
        pipe(c0, c1, 2);
    } else {
        pipe(c0, c0, 1);   // sequential, shared buffer set
        pipe(c1, c1, 1);
    }
}